// Round 1
// baseline (2129.105 us; speedup 1.0000x reference)
//
#include <hip/hip_runtime.h>

// Problem constants
static constexpr int Hc  = 512;   // hidden
static constexpr int NHc = 8;     // heads
static constexpr int DHc = 64;    // head dim
static constexpr int NLc = 2;     // layers
static constexpr int Rc  = 64;    // relation types
static constexpr int FFc = 2048;  // ffn inner
static constexpr int Bc  = 4;
static constexpr int Tc  = 512;
static constexpr int Sc  = 512;
#define NEGV (-1e10f)
#define EPSV 1e-5f

// ---------------------------------------------------------------------------
// Tiled f32 GEMM: C[M,N] = A[M,K] @ W[K,N] (+bias) (+relu)
// BM=BN=64, BK=16, 256 threads, 4x4 micro-tile per thread.
// M,N,K all multiples of 64/16 in this problem — no bounds checks.
// ---------------------------------------------------------------------------
template <bool RELU>
__global__ __launch_bounds__(256) void gemm64(
    const float* __restrict__ A, const float* __restrict__ W,
    const float* __restrict__ bias, float* __restrict__ C,
    int M, int N, int K) {
  __shared__ float As[16][64];
  __shared__ float Ws[16][64];
  const int tid = threadIdx.x;
  const int bn = blockIdx.x * 64;
  const int bm = blockIdx.y * 64;

  const int arow = tid >> 2;            // 0..63
  const int akq  = (tid & 3) * 4;       // 0,4,8,12
  const int wrow = tid >> 4;            // 0..15
  const int wcq  = (tid & 15) * 4;      // 0..60
  const int tx4  = (tid & 15) * 4;
  const int ty4  = (tid >> 4) * 4;

  float acc[4][4] = {};

  for (int k0 = 0; k0 < K; k0 += 16) {
    float4 av = *(const float4*)&A[(size_t)(bm + arow) * K + k0 + akq];
    float4 wv = *(const float4*)&W[(size_t)(k0 + wrow) * N + bn + wcq];
    __syncthreads();  // previous-iteration readers done before overwrite
    As[akq + 0][arow] = av.x;
    As[akq + 1][arow] = av.y;
    As[akq + 2][arow] = av.z;
    As[akq + 3][arow] = av.w;
    *(float4*)&Ws[wrow][wcq] = wv;
    __syncthreads();
#pragma unroll
    for (int k = 0; k < 16; ++k) {
      float4 a = *(const float4*)&As[k][ty4];
      float4 b = *(const float4*)&Ws[k][tx4];
      float ar[4] = {a.x, a.y, a.z, a.w};
      float br[4] = {b.x, b.y, b.z, b.w};
#pragma unroll
      for (int i = 0; i < 4; ++i)
#pragma unroll
        for (int j = 0; j < 4; ++j) acc[i][j] += ar[i] * br[j];
    }
  }

  float4 bv = {0.f, 0.f, 0.f, 0.f};
  if (bias) bv = *(const float4*)&bias[bn + tx4];
#pragma unroll
  for (int i = 0; i < 4; ++i) {
    float4 c;
    c.x = acc[i][0] + bv.x;
    c.y = acc[i][1] + bv.y;
    c.z = acc[i][2] + bv.z;
    c.w = acc[i][3] + bv.w;
    if (RELU) {
      c.x = fmaxf(c.x, 0.f); c.y = fmaxf(c.y, 0.f);
      c.z = fmaxf(c.z, 0.f); c.w = fmaxf(c.w, 0.f);
    }
    *(float4*)&C[(size_t)(bm + ty4 + i) * N + bn + tx4] = c;
  }
}

// ---------------------------------------------------------------------------
// Qr[row, r] = sum_d Q[row, d] * rel_emb_k[r, d]
// Q viewed as (B*T*NH, DH) contiguous rows. 4 rows per 256-thread block.
// ---------------------------------------------------------------------------
__global__ __launch_bounds__(256) void qr_kernel(
    const float* __restrict__ Q, const float* __restrict__ relk,
    float* __restrict__ Qr) {
  __shared__ float rk_s[Rc][DHc + 1];  // +1 pad: lane-r reads -> ~2-way max
  __shared__ float q_s[4][DHc];
  const int tid = threadIdx.x;
#pragma unroll
  for (int i = 0; i < 4; ++i) {
    int lin = i * 1024 + tid * 4;
    int r = lin >> 6, d = lin & 63;
    float4 v = *(const float4*)&relk[lin];
    rk_s[r][d + 0] = v.x; rk_s[r][d + 1] = v.y;
    rk_s[r][d + 2] = v.z; rk_s[r][d + 3] = v.w;
  }
  const int sub = tid >> 6;
  const int r = tid & 63;
  const int row = blockIdx.x * 4 + sub;
  q_s[sub][r] = Q[(size_t)row * DHc + r];  // coalesced: blockIdx*256 + tid
  __syncthreads();
  float acc = 0.f;
#pragma unroll
  for (int d = 0; d < DHc; ++d) acc += q_s[sub][d] * rk_s[r][d];
  Qr[(size_t)row * Rc + r] = acc;
}

// ---------------------------------------------------------------------------
// Fused relation-aware masked self-attention. One block per (b,h,l).
// e[m] = (Q.K[m] + Qr[rel[m]])/8, masked to NEG; softmax; out = a.V + buck@relv
// ---------------------------------------------------------------------------
__global__ __launch_bounds__(256) void attn_self(
    const float* __restrict__ Q, const float* __restrict__ Kb,
    const float* __restrict__ Vb, const float* __restrict__ Qr,
    const int* __restrict__ rel_ids, const float* __restrict__ relv,
    float* __restrict__ att) {
  __shared__ float q_s[DHc];
  __shared__ float qr_s[Rc];
  __shared__ float p_s[Tc];
  __shared__ int rel_s[Tc];
  __shared__ float red_s[256];
  __shared__ float av_s[4][DHc];
  __shared__ float buck_s[Rc];

  const int tid = threadIdx.x;
  const int l = blockIdx.x & (Tc - 1);
  const int h = (blockIdx.x >> 9) & (NHc - 1);
  const int b = blockIdx.x >> 12;
  const int row = b * Tc + l;
  const int qoff = (row * NHc + h) * DHc;  // == row*H + h*DH

  if (tid < DHc) q_s[tid] = Q[qoff + tid];
  else if (tid < 2 * DHc) qr_s[tid - DHc] = Qr[(size_t)(row * NHc + h) * Rc + (tid - DHc)];
  else if (tid < 3 * DHc) buck_s[tid - 2 * DHc] = 0.f;
  rel_s[tid] = rel_ids[(size_t)row * Tc + tid];
  rel_s[tid + 256] = rel_ids[(size_t)row * Tc + tid + 256];
  __syncthreads();

  const float* Kbase = Kb + (size_t)(b * Tc) * Hc + h * DHc;
  const int m0 = tid, m1 = tid + 256;
  float acc0 = 0.f, acc1 = 0.f;
  {
    const float4* kp0 = (const float4*)(Kbase + (size_t)m0 * Hc);
    const float4* kp1 = (const float4*)(Kbase + (size_t)m1 * Hc);
#pragma unroll
    for (int j = 0; j < 16; ++j) {
      float4 k0v = kp0[j];
      float4 k1v = kp1[j];
      float qx = q_s[4 * j], qy = q_s[4 * j + 1], qz = q_s[4 * j + 2], qw = q_s[4 * j + 3];
      acc0 += k0v.x * qx + k0v.y * qy + k0v.z * qz + k0v.w * qw;
      acc1 += k1v.x * qx + k1v.y * qy + k1v.z * qz + k1v.w * qw;
    }
  }
  const int r0 = rel_s[m0], r1 = rel_s[m1];
  float e0 = (r0 != 0 && m0 <= l) ? (acc0 + qr_s[r0]) * 0.125f : NEGV;
  float e1 = (r1 != 0 && m1 <= l) ? (acc1 + qr_s[r1]) * 0.125f : NEGV;

  // max reduce
  red_s[tid] = fmaxf(e0, e1);
  __syncthreads();
  for (int s = 128; s > 0; s >>= 1) {
    if (tid < s) red_s[tid] = fmaxf(red_s[tid], red_s[tid + s]);
    __syncthreads();
  }
  const float mx = red_s[0];
  __syncthreads();

  float p0 = __expf(e0 - mx), p1 = __expf(e1 - mx);
  p_s[m0] = p0;
  p_s[m1] = p1;
  atomicAdd(&buck_s[r0], p0);
  atomicAdd(&buck_s[r1], p1);

  // sum reduce
  red_s[tid] = p0 + p1;
  __syncthreads();
  for (int s = 128; s > 0; s >>= 1) {
    if (tid < s) red_s[tid] += red_s[tid + s];
    __syncthreads();
  }
  const float denom = red_s[0];
  __syncthreads();

  // AV: lane d, chunk c over m
  const int d = tid & 63, c = tid >> 6;
  const float* Vbase = Vb + (size_t)(b * Tc) * Hc + h * DHc + d;
  float acc = 0.f;
  for (int m = c * 128; m < c * 128 + 128; ++m) acc += p_s[m] * Vbase[(size_t)m * Hc];
  av_s[c][d] = acc;
  __syncthreads();

  if (tid < DHc) {
    float s = av_s[0][tid] + av_s[1][tid] + av_s[2][tid] + av_s[3][tid];
#pragma unroll
    for (int r = 0; r < Rc; ++r) s += buck_s[r] * relv[r * DHc + tid];
    att[qoff + tid] = s * (1.f / denom);
  }
}

// ---------------------------------------------------------------------------
// Cross-attention (enc_mask is all-True in this problem: no masking).
// ---------------------------------------------------------------------------
__global__ __launch_bounds__(256) void attn_cross(
    const float* __restrict__ Q, const float* __restrict__ Kb,
    const float* __restrict__ Vb, float* __restrict__ att) {
  __shared__ float q_s[DHc];
  __shared__ float p_s[Sc];
  __shared__ float red_s[256];
  __shared__ float av_s[4][DHc];

  const int tid = threadIdx.x;
  const int t = blockIdx.x & (Tc - 1);
  const int h = (blockIdx.x >> 9) & (NHc - 1);
  const int b = blockIdx.x >> 12;
  const int qoff = ((b * Tc + t) * NHc + h) * DHc;

  if (tid < DHc) q_s[tid] = Q[qoff + tid];
  __syncthreads();

  const float* Kbase = Kb + (size_t)(b * Sc) * Hc + h * DHc;
  const int m0 = tid, m1 = tid + 256;
  float acc0 = 0.f, acc1 = 0.f;
  {
    const float4* kp0 = (const float4*)(Kbase + (size_t)m0 * Hc);
    const float4* kp1 = (const float4*)(Kbase + (size_t)m1 * Hc);
#pragma unroll
    for (int j = 0; j < 16; ++j) {
      float4 k0v = kp0[j];
      float4 k1v = kp1[j];
      float qx = q_s[4 * j], qy = q_s[4 * j + 1], qz = q_s[4 * j + 2], qw = q_s[4 * j + 3];
      acc0 += k0v.x * qx + k0v.y * qy + k0v.z * qz + k0v.w * qw;
      acc1 += k1v.x * qx + k1v.y * qy + k1v.z * qz + k1v.w * qw;
    }
  }
  float e0 = acc0 * 0.125f, e1 = acc1 * 0.125f;

  red_s[tid] = fmaxf(e0, e1);
  __syncthreads();
  for (int s = 128; s > 0; s >>= 1) {
    if (tid < s) red_s[tid] = fmaxf(red_s[tid], red_s[tid + s]);
    __syncthreads();
  }
  const float mx = red_s[0];
  __syncthreads();

  float p0 = __expf(e0 - mx), p1 = __expf(e1 - mx);
  p_s[m0] = p0;
  p_s[m1] = p1;
  red_s[tid] = p0 + p1;
  __syncthreads();
  for (int s = 128; s > 0; s >>= 1) {
    if (tid < s) red_s[tid] += red_s[tid + s];
    __syncthreads();
  }
  const float denom = red_s[0];
  __syncthreads();

  const int d = tid & 63, c = tid >> 6;
  const float* Vbase = Vb + (size_t)(b * Sc) * Hc + h * DHc + d;
  float acc = 0.f;
  for (int m = c * 128; m < c * 128 + 128; ++m) acc += p_s[m] * Vbase[(size_t)m * Hc];
  av_s[c][d] = acc;
  __syncthreads();

  if (tid < DHc) {
    float s = av_s[0][tid] + av_s[1][tid] + av_s[2][tid] + av_s[3][tid];
    att[qoff + tid] = s * (1.f / denom);
  }
}

// ---------------------------------------------------------------------------
// out = LayerNorm(x + dlt) * g + b ; one block per row (H=512, 2 elems/thread)
// Safe in-place (all reads precede writes via the reduction barriers).
// ---------------------------------------------------------------------------
__global__ __launch_bounds__(256) void ln_res(
    const float* __restrict__ x, const float* __restrict__ dlt,
    const float* __restrict__ g, const float* __restrict__ bta,
    float* __restrict__ out) {
  __shared__ float red_s[256];
  const int row = blockIdx.x, tid = threadIdx.x;
  const size_t base = (size_t)row * Hc;
  float v0 = x[base + tid] + dlt[base + tid];
  float v1 = x[base + tid + 256] + dlt[base + tid + 256];

  red_s[tid] = v0 + v1;
  __syncthreads();
  for (int s = 128; s > 0; s >>= 1) {
    if (tid < s) red_s[tid] += red_s[tid + s];
    __syncthreads();
  }
  const float mean = red_s[0] * (1.f / Hc);
  __syncthreads();

  const float d0 = v0 - mean, d1 = v1 - mean;
  red_s[tid] = d0 * d0 + d1 * d1;
  __syncthreads();
  for (int s = 128; s > 0; s >>= 1) {
    if (tid < s) red_s[tid] += red_s[tid + s];
    __syncthreads();
  }
  const float rstd = rsqrtf(red_s[0] * (1.f / Hc) + EPSV);
  out[base + tid] = d0 * rstd * g[tid] + bta[tid];
  out[base + tid + 256] = d1 * rstd * g[tid + 256] + bta[tid + 256];
}

// ---------------------------------------------------------------------------
extern "C" void kernel_launch(void* const* d_in, const int* in_sizes, int n_in,
                              void* d_out, int out_size, void* d_ws, size_t ws_size,
                              hipStream_t stream) {
  const float* q    = (const float*)d_in[0];
  const float* kv   = (const float*)d_in[1];
  const float* relk = (const float*)d_in[2];
  const float* relv = (const float*)d_in[3];
  const float* Wq_s = (const float*)d_in[4];
  const float* bq_s = (const float*)d_in[5];
  const float* Wk_s = (const float*)d_in[6];
  const float* Wv_s = (const float*)d_in[7];
  const float* Wo_s = (const float*)d_in[8];
  const float* bo_s = (const float*)d_in[9];
  const float* ln1g = (const float*)d_in[10];
  const float* ln1b = (const float*)d_in[11];
  const float* Wq_c = (const float*)d_in[12];
  const float* bq_c = (const float*)d_in[13];
  const float* Wk_c = (const float*)d_in[14];
  const float* Wv_c = (const float*)d_in[15];
  const float* Wo_c = (const float*)d_in[16];
  const float* bo_c = (const float*)d_in[17];
  const float* ln2g = (const float*)d_in[18];
  const float* ln2b = (const float*)d_in[19];
  const float* W1   = (const float*)d_in[20];
  const float* b1   = (const float*)d_in[21];
  const float* W2   = (const float*)d_in[22];
  const float* b2   = (const float*)d_in[23];
  const float* ln3g = (const float*)d_in[24];
  const float* ln3b = (const float*)d_in[25];
  const int*   rel  = (const int*)d_in[26];
  // d_in[27] enc_mask: all-True by construction — no masking applied.

  float* ws = (float*)d_ws;
  const size_t NTOK = (size_t)Bc * Tc * Hc;  // 1,048,576 floats
  float* o    = ws;
  float* bQ   = ws + 1 * NTOK;
  float* bK   = ws + 2 * NTOK;
  float* bV   = ws + 3 * NTOK;
  float* bQr  = ws + 4 * NTOK;
  float* bAtt = ws + 5 * NTOK;
  float* bDlt = ws + 6 * NTOK;
  float* bH   = bQ;  // FFN hidden (4*NTOK floats) aliases dead bQ..bQr region

  hipMemcpyAsync(o, q, NTOK * sizeof(float), hipMemcpyDeviceToDevice, stream);

  const int M = Bc * Tc;  // 2048 rows (also B*S for kv)
  dim3 blk(256);
  const dim3 gHH(Hc / 64, M / 64);    // H-wide GEMMs
  const dim3 gFF(FFc / 64, M / 64);   // FFN up
  const dim3 gATT(Bc * NHc * Tc);     // 16384 rows
  const dim3 gQR(M * NHc / 4);        // 4096
  const dim3 gLN(M);

  for (int i = 0; i < NLc; ++i) {
    const size_t wHH = (size_t)i * Hc * Hc;
    // --- relation-aware masked self-attention ---
    gemm64<false><<<gHH, blk, 0, stream>>>(o, Wq_s + wHH, bq_s + i * Hc, bQ, M, Hc, Hc);
    gemm64<false><<<gHH, blk, 0, stream>>>(o, Wk_s + wHH, nullptr, bK, M, Hc, Hc);
    gemm64<false><<<gHH, blk, 0, stream>>>(o, Wv_s + wHH, nullptr, bV, M, Hc, Hc);
    qr_kernel<<<gQR, blk, 0, stream>>>(bQ, relk, bQr);
    attn_self<<<gATT, blk, 0, stream>>>(bQ, bK, bV, bQr, rel, relv, bAtt);
    gemm64<false><<<gHH, blk, 0, stream>>>(bAtt, Wo_s + wHH, bo_s + i * Hc, bDlt, M, Hc, Hc);
    ln_res<<<gLN, blk, 0, stream>>>(o, bDlt, ln1g + i * Hc, ln1b + i * Hc, o);

    // --- cross-attention ---
    gemm64<false><<<gHH, blk, 0, stream>>>(o, Wq_c + wHH, bq_c + i * Hc, bQ, M, Hc, Hc);
    gemm64<false><<<gHH, blk, 0, stream>>>(kv, Wk_c + wHH, nullptr, bK, M, Hc, Hc);
    gemm64<false><<<gHH, blk, 0, stream>>>(kv, Wv_c + wHH, nullptr, bV, M, Hc, Hc);
    attn_cross<<<gATT, blk, 0, stream>>>(bQ, bK, bV, bAtt);
    gemm64<false><<<gHH, blk, 0, stream>>>(bAtt, Wo_c + wHH, bo_c + i * Hc, bDlt, M, Hc, Hc);
    ln_res<<<gLN, blk, 0, stream>>>(o, bDlt, ln2g + i * Hc, ln2b + i * Hc, o);

    // --- feedforward ---
    gemm64<true><<<gFF, blk, 0, stream>>>(o, W1 + (size_t)i * Hc * FFc, b1 + i * FFc, bH, M, FFc, Hc);
    gemm64<false><<<gHH, blk, 0, stream>>>(bH, W2 + (size_t)i * FFc * Hc, b2 + i * Hc, bDlt, M, Hc, FFc);
    float* lnout = (i == NLc - 1) ? (float*)d_out : o;
    ln_res<<<gLN, blk, 0, stream>>>(o, bDlt, ln3g + i * Hc, ln3b + i * Hc, lnout);
  }
}

// Round 2
// 481.867 us; speedup vs baseline: 4.4185x; 4.4185x over previous
//
#include <hip/hip_runtime.h>

static constexpr int Hc  = 512;
static constexpr int NHc = 8;
static constexpr int DHc = 64;
static constexpr int NLc = 2;
static constexpr int Rc  = 64;
static constexpr int FFc = 2048;
static constexpr int Bc  = 4;
static constexpr int Tc  = 512;
#define NEGV (-1e10f)
#define EPSV 1e-5f

typedef unsigned short u16;
typedef __attribute__((ext_vector_type(8))) short s16x8;
typedef __attribute__((ext_vector_type(4))) float f32x4;

__device__ __forceinline__ f32x4 mfma_bf16(s16x8 a, s16x8 b, f32x4 c) {
  return __builtin_amdgcn_mfma_f32_16x16x32_bf16(a, b, c, 0, 0, 0);
}
__device__ __forceinline__ u16 f2bf(float f) {
  union { float f; unsigned u; } x; x.f = f;
  unsigned r = (x.u + 0x7FFFu + ((x.u >> 16) & 1u)) >> 16;
  return (u16)r;
}
__device__ __forceinline__ float bf2f(u16 h) {
  union { unsigned u; float f; } x; x.u = ((unsigned)h) << 16;
  return x.f;
}

// ---------------------------------------------------------------------------
// bf16 MFMA GEMM: C[M,N] = A[M,K](bf16) @ Wt[N,K]^T(bf16) (+bias<biasN) (+relu)
// BN=128, BK=32, 256 threads (4 waves, 2x2), wave computes (BM/2)x64.
// LDS tiles [rows][32] bf16, 16B-chunk XOR swizzle (ch ^= row&3) on write+read.
// ---------------------------------------------------------------------------
template <int BM, bool RELU, int OUT>  // OUT: 0=f32, 1=bf16
__global__ __launch_bounds__(256) void gemm_mfma(
    const u16* __restrict__ A, const u16* __restrict__ Wt,
    const float* __restrict__ bias, int biasN,
    void* __restrict__ Cout, int N, int K) {
  __shared__ u16 As[BM * 32];
  __shared__ u16 Bs[128 * 32];
  const int tid = threadIdx.x;
  const int w = tid >> 6, lane = tid & 63, g = lane >> 4, li = lane & 15;
  const int bn = blockIdx.x * 128, bm = blockIdx.y * BM;
  const int r0 = (w & 1) * (BM / 2), c0 = (w >> 1) * 64;
  constexpr int MR = BM / 32;
  f32x4 acc[MR][4];
#pragma unroll
  for (int i = 0; i < MR; ++i)
#pragma unroll
    for (int j = 0; j < 4; ++j) acc[i][j] = (f32x4){0.f, 0.f, 0.f, 0.f};

  for (int k0 = 0; k0 < K; k0 += 32) {
    __syncthreads();
#pragma unroll
    for (int it = 0; it < BM / 64; ++it) {
      int s = it * 256 + tid;
      int row = s >> 2, ch = s & 3;
      s16x8 v = *(const s16x8*)(A + (size_t)(bm + row) * K + k0 + ch * 8);
      *(s16x8*)&As[row * 32 + ((ch ^ (row & 3)) * 8)] = v;
    }
#pragma unroll
    for (int it = 0; it < 2; ++it) {
      int s = it * 256 + tid;
      int row = s >> 2, ch = s & 3;
      s16x8 v = *(const s16x8*)(Wt + (size_t)(bn + row) * K + k0 + ch * 8);
      *(s16x8*)&Bs[row * 32 + ((ch ^ (row & 3)) * 8)] = v;
    }
    __syncthreads();
    s16x8 ar[MR], br[4];
#pragma unroll
    for (int i = 0; i < MR; ++i) {
      int row = r0 + i * 16 + li;
      ar[i] = *(const s16x8*)&As[row * 32 + ((g ^ (row & 3)) * 8)];
    }
#pragma unroll
    for (int j = 0; j < 4; ++j) {
      int row = c0 + j * 16 + li;
      br[j] = *(const s16x8*)&Bs[row * 32 + ((g ^ (row & 3)) * 8)];
    }
#pragma unroll
    for (int i = 0; i < MR; ++i)
#pragma unroll
      for (int j = 0; j < 4; ++j) acc[i][j] = mfma_bf16(ar[i], br[j], acc[i][j]);
  }

#pragma unroll
  for (int j = 0; j < 4; ++j) {
    int col = bn + c0 + j * 16 + li;
    float bv = (col < biasN) ? bias[col] : 0.f;
#pragma unroll
    for (int i = 0; i < MR; ++i) {
#pragma unroll
      for (int r = 0; r < 4; ++r) {
        int rowg = bm + r0 + i * 16 + 4 * g + r;
        float v = acc[i][j][r] + bv;
        if (RELU) v = fmaxf(v, 0.f);
        if (OUT == 0) ((float*)Cout)[(size_t)rowg * N + col] = v;
        else          ((u16*)Cout)[(size_t)rowg * N + col] = f2bf(v);
      }
    }
  }
}

// ---------------------------------------------------------------------------
// Weight transpose+convert: 20 f32 [Ks][Ns] matrices -> bf16 [Ns][Ks] at dstOff
// ---------------------------------------------------------------------------
struct WPtrs { const float* p[10]; };

__global__ __launch_bounds__(256) void wcvt(WPtrs wp, u16* __restrict__ dst) {
  constexpr int NE = 20;
  constexpr int srcIdx[NE] = {0,1,2,0,1,2,3,3,4,4,7,7,8,8,9,9,5,6,5,6};
  constexpr int srcOff[NE] = {0,0,0,262144,262144,262144,0,262144,0,262144,
                              0,262144,0,1048576,0,1048576,0,0,262144,262144};
  constexpr int dstOff[NE] = {0,262144,524288,786432,1048576,1310720,
                              1572864,1835008,2097152,2359296,2621440,2883584,
                              3145728,4194304,5242880,6291456,
                              7340032,7602176,7864320,8126464};
  constexpr int KsA[NE] = {512,512,512,512,512,512,512,512,512,512,512,512,
                           512,512,2048,2048,512,512,512,512};
  constexpr int NsA[NE] = {512,512,512,512,512,512,512,512,512,512,512,512,
                           2048,2048,512,512,512,512,512,512};
  constexpr int tileStart[NE] = {0,64,128,192,256,320,384,448,512,576,640,704,
                                 768,1024,1280,1536,1792,1856,1920,1984};
  __shared__ float ts[64 * 65];
  const int tid = threadIdx.x;
  const int bid = blockIdx.x;
  int e = 0;
#pragma unroll
  for (int i = 1; i < NE; ++i) if (bid >= tileStart[i]) e = i;
  const int t = bid - tileStart[e];
  const int Ks_ = KsA[e], Ns_ = NsA[e];
  const int tn = t % (Ns_ >> 6), tk = t / (Ns_ >> 6);
  const float* src = wp.p[srcIdx[e]] + srcOff[e];

  {
    int r = tid >> 2, cb = (tid & 3) * 16;
    const float* sp = src + (size_t)(tk * 64 + r) * Ns_ + tn * 64 + cb;
#pragma unroll
    for (int j = 0; j < 4; ++j) {
      float4 v = ((const float4*)sp)[j];
      float* d = &ts[r * 65 + cb + j * 4];
      d[0] = v.x; d[1] = v.y; d[2] = v.z; d[3] = v.w;
    }
  }
  __syncthreads();
  {
    int n = tid >> 2, kb = (tid & 3) * 16;
    u16* dp = dst + dstOff[e] + (size_t)(tn * 64 + n) * Ks_ + tk * 64 + kb;
    s16x8 o0, o1;
#pragma unroll
    for (int j = 0; j < 8; ++j) o0[j] = (short)f2bf(ts[(kb + j) * 65 + n]);
#pragma unroll
    for (int j = 0; j < 8; ++j) o1[j] = (short)f2bf(ts[(kb + 8 + j) * 65 + n]);
    *(s16x8*)dp = o0;
    *(s16x8*)(dp + 8) = o1;
  }
}

// ---------------------------------------------------------------------------
// f32 -> bf16 activation convert (q -> obf, kv -> kvbf), 8 elems/thread
// ---------------------------------------------------------------------------
__global__ __launch_bounds__(256) void acvt(
    const float* __restrict__ q, const float* __restrict__ kv,
    u16* __restrict__ obf, u16* __restrict__ kvbf) {
  int i = blockIdx.x * 256 + threadIdx.x;
  const float* src; u16* dst; size_t off;
  if (i < 131072) { src = q; dst = obf; off = (size_t)i * 8; }
  else { src = kv; dst = kvbf; off = (size_t)(i - 131072) * 8; }
  float4 a = *(const float4*)(src + off);
  float4 b = *(const float4*)(src + off + 4);
  s16x8 o;
  o[0] = (short)f2bf(a.x); o[1] = (short)f2bf(a.y);
  o[2] = (short)f2bf(a.z); o[3] = (short)f2bf(a.w);
  o[4] = (short)f2bf(b.x); o[5] = (short)f2bf(b.y);
  o[6] = (short)f2bf(b.z); o[7] = (short)f2bf(b.w);
  *(s16x8*)(dst + off) = o;
}

// ---------------------------------------------------------------------------
// Qr[(row*8+h), r] = sum_d Q[row, h*64+d] * relk[r, d]   (Q bf16, stride 1536)
// ---------------------------------------------------------------------------
__global__ __launch_bounds__(256) void qr_kernel(
    const u16* __restrict__ Q, const float* __restrict__ relk,
    float* __restrict__ Qr) {
  __shared__ float rk[64 * 65];
  __shared__ float qs[4][64];
  const int tid = threadIdx.x;
  {
    int r = tid >> 2, cb = (tid & 3) * 16;
    const float* sp = relk + r * 64 + cb;
#pragma unroll
    for (int j = 0; j < 4; ++j) {
      float4 v = ((const float4*)sp)[j];
      float* d = &rk[r * 65 + cb + j * 4];
      d[0] = v.x; d[1] = v.y; d[2] = v.z; d[3] = v.w;
    }
  }
  const int sub = tid >> 6, r = tid & 63;
  const int unit = blockIdx.x * 4 + sub;  // unit = row*8 + h
  qs[sub][r] = bf2f(Q[(size_t)(unit >> 3) * 1536 + (unit & 7) * 64 + r]);
  __syncthreads();
  float acc = 0.f;
#pragma unroll
  for (int d = 0; d < 64; ++d) acc += qs[sub][d] * rk[r * 65 + d];
  Qr[(size_t)unit * 64 + r] = acc;
}

// ---------------------------------------------------------------------------
// Two-pass MFMA attention. Block = (q-tile of 64, head, batch), 256 thr.
// SELF: rel-aware masked self-attn (Qr gather + rel-V buckets + tril mask).
// ---------------------------------------------------------------------------
template <bool SELF>
__global__ __launch_bounds__(256) void attn_mfma(
    const u16* __restrict__ qbase, int qstride,
    const u16* __restrict__ kbase, const u16* __restrict__ vbase, int kvstride,
    const float* __restrict__ Qr, const int* __restrict__ rel_ids,
    const float* __restrict__ relv, u16* __restrict__ att) {
  __shared__ u16 Ks[64 * 64];     // [m][d] swizzled
  __shared__ u16 Vt[64 * 64];     // [d][m] swizzled
  __shared__ u16 Ps[64 * 64];     // [l][m] swizzled
  __shared__ float qr_s[64 * 64]; // [l][r]
  __shared__ float buck[64 * 64]; // [l][r]
  __shared__ float rv_s[64 * 64]; // [r][d]
  __shared__ int rel_s[64 * 64];  // [l][m]

  const int tid = threadIdx.x;
  const int w = tid >> 6, lane = tid & 63, g = lane >> 4, li = lane & 15;
  const int qt = blockIdx.x, h = blockIdx.y, b = blockIdx.z;
  const int l0 = w * 16;
  const int rowq0 = b * Tc + qt * 64;

  // Q fragments held in registers for the whole kernel
  s16x8 aq[2];
  {
    const u16* qp = qbase + (size_t)(rowq0 + l0 + li) * qstride + h * 64;
    aq[0] = *(const s16x8*)(qp + g * 8);
    aq[1] = *(const s16x8*)(qp + 32 + g * 8);
  }
  if (SELF) {
    int l = tid >> 2, cb = (tid & 3) * 16;
    const float* qp = Qr + ((size_t)(rowq0 + l) * 8 + h) * 64 + cb;
    const float* rp = relv + l * 64 + cb;  // reuse (l,cb) as (r,db)
#pragma unroll
    for (int j = 0; j < 4; ++j) {
      *(float4*)&qr_s[l * 64 + cb + j * 4] = ((const float4*)qp)[j];
      *(float4*)&rv_s[l * 64 + cb + j * 4] = ((const float4*)rp)[j];
      *(float4*)&buck[l * 64 + cb + j * 4] = (float4){0.f, 0.f, 0.f, 0.f};
    }
  }

  float mx[4] = {NEGV, NEGV, NEGV, NEGV};

  // ---------------- pass 1: row max ----------------
  for (int c8 = 0; c8 < 8; ++c8) {
    __syncthreads();
    {  // stage K chunk
      int m = tid >> 2, db = (tid & 3) * 16;
      const u16* kp = kbase + (size_t)(b * Tc + c8 * 64 + m) * kvstride + h * 64 + db;
      s16x8 v0 = *(const s16x8*)kp;
      s16x8 v1 = *(const s16x8*)(kp + 8);
      int c0c = db >> 3;
      *(s16x8*)&Ks[m * 64 + ((c0c ^ (m & 7)) * 8)] = v0;
      *(s16x8*)&Ks[m * 64 + (((c0c + 1) ^ (m & 7)) * 8)] = v1;
    }
    if (SELF) {  // stage rel chunk
      int l = tid >> 2, mb = (tid & 3) * 16;
      const int* rp = rel_ids + (size_t)(b * Tc + qt * 64 + l) * Tc + c8 * 64 + mb;
#pragma unroll
      for (int j = 0; j < 4; ++j)
        *(int4*)&rel_s[l * 64 + mb + j * 4] = ((const int4*)rp)[j];
    }
    __syncthreads();
    f32x4 sf[4];
#pragma unroll
    for (int cf = 0; cf < 4; ++cf) {
      sf[cf] = (f32x4){0.f, 0.f, 0.f, 0.f};
      int row = cf * 16 + li;
#pragma unroll
      for (int kk = 0; kk < 2; ++kk) {
        s16x8 bk = *(const s16x8*)&Ks[row * 64 + (((kk * 4 + g) ^ (row & 7)) * 8)];
        sf[cf] = mfma_bf16(aq[kk], bk, sf[cf]);
      }
    }
#pragma unroll
    for (int cf = 0; cf < 4; ++cf) {
#pragma unroll
      for (int r = 0; r < 4; ++r) {
        int lrow = 4 * g + r;
        float e;
        if (SELF) {
          int rel = rel_s[(l0 + lrow) * 64 + cf * 16 + li];
          bool valid = (rel != 0) && (c8 * 64 + cf * 16 + li <= qt * 64 + l0 + lrow);
          e = valid ? (sf[cf][r] + qr_s[(l0 + lrow) * 64 + rel]) * 0.125f : NEGV;
        } else {
          e = sf[cf][r] * 0.125f;
        }
        mx[r] = fmaxf(mx[r], e);
      }
    }
  }
  bool am[4];
#pragma unroll
  for (int r = 0; r < 4; ++r) {
#pragma unroll
    for (int msk = 1; msk < 16; msk <<= 1) mx[r] = fmaxf(mx[r], __shfl_xor(mx[r], msk));
    am[r] = SELF && (mx[r] < -1e9f);
  }

  // ---------------- pass 2: exp, buckets, PV ----------------
  f32x4 oacc[4];
#pragma unroll
  for (int d = 0; d < 4; ++d) oacc[d] = (f32x4){0.f, 0.f, 0.f, 0.f};
  float rs[4] = {0.f, 0.f, 0.f, 0.f};

  for (int c8 = 0; c8 < 8; ++c8) {
    __syncthreads();  // previous chunk's Ps/Vt reads done
    {  // stage K
      int m = tid >> 2, db = (tid & 3) * 16;
      const u16* kp = kbase + (size_t)(b * Tc + c8 * 64 + m) * kvstride + h * 64 + db;
      s16x8 v0 = *(const s16x8*)kp;
      s16x8 v1 = *(const s16x8*)(kp + 8);
      int c0c = db >> 3;
      *(s16x8*)&Ks[m * 64 + ((c0c ^ (m & 7)) * 8)] = v0;
      *(s16x8*)&Ks[m * 64 + (((c0c + 1) ^ (m & 7)) * 8)] = v1;
    }
    {  // stage V transposed
      int m = tid >> 2, db = (tid & 3) * 16;
      const u16* vp = vbase + (size_t)(b * Tc + c8 * 64 + m) * kvstride + h * 64 + db;
      s16x8 v0 = *(const s16x8*)vp;
      s16x8 v1 = *(const s16x8*)(vp + 8);
#pragma unroll
      for (int e = 0; e < 8; ++e) {
        int d0 = db + e, d1 = db + 8 + e;
        Vt[d0 * 64 + (((m >> 3) ^ (d0 & 7)) * 8) + (m & 7)] = (u16)v0[e];
        Vt[d1 * 64 + (((m >> 3) ^ (d1 & 7)) * 8) + (m & 7)] = (u16)v1[e];
      }
    }
    if (SELF) {
      int l = tid >> 2, mb = (tid & 3) * 16;
      const int* rp = rel_ids + (size_t)(b * Tc + qt * 64 + l) * Tc + c8 * 64 + mb;
#pragma unroll
      for (int j = 0; j < 4; ++j)
        *(int4*)&rel_s[l * 64 + mb + j * 4] = ((const int4*)rp)[j];
    }
    __syncthreads();
    f32x4 sf[4];
#pragma unroll
    for (int cf = 0; cf < 4; ++cf) {
      sf[cf] = (f32x4){0.f, 0.f, 0.f, 0.f};
      int row = cf * 16 + li;
#pragma unroll
      for (int kk = 0; kk < 2; ++kk) {
        s16x8 bk = *(const s16x8*)&Ks[row * 64 + (((kk * 4 + g) ^ (row & 7)) * 8)];
        sf[cf] = mfma_bf16(aq[kk], bk, sf[cf]);
      }
    }
#pragma unroll
    for (int cf = 0; cf < 4; ++cf) {
#pragma unroll
      for (int r = 0; r < 4; ++r) {
        int lrow = 4 * g + r;
        int col = cf * 16 + li;
        float p;
        if (SELF) {
          int rel = rel_s[(l0 + lrow) * 64 + col];
          if (am[r]) {
            p = 1.0f;
          } else {
            bool valid = (rel != 0) && (c8 * 64 + col <= qt * 64 + l0 + lrow);
            p = valid ? __expf((sf[cf][r] + qr_s[(l0 + lrow) * 64 + rel]) * 0.125f - mx[r]) : 0.f;
          }
          if (p != 0.f) atomicAdd(&buck[(l0 + lrow) * 64 + rel], p);
        } else {
          p = __expf(sf[cf][r] * 0.125f - mx[r]);
        }
        rs[r] += p;
        int prow = l0 + lrow;
        Ps[prow * 64 + (((col >> 3) ^ (prow & 7)) * 8) + (col & 7)] = f2bf(p);
      }
    }
    __syncthreads();  // Ps/Vt ready
    s16x8 pa[2];
    {
      int prow = l0 + li;
#pragma unroll
      for (int kk = 0; kk < 2; ++kk)
        pa[kk] = *(const s16x8*)&Ps[prow * 64 + (((kk * 4 + g) ^ (prow & 7)) * 8)];
    }
#pragma unroll
    for (int df = 0; df < 4; ++df) {
      int row = df * 16 + li;
#pragma unroll
      for (int kk = 0; kk < 2; ++kk) {
        s16x8 bv = *(const s16x8*)&Vt[row * 64 + (((kk * 4 + g) ^ (row & 7)) * 8)];
        oacc[df] = mfma_bf16(pa[kk], bv, oacc[df]);
      }
    }
  }
  __syncthreads();  // bucket atomics drained

#pragma unroll
  for (int r = 0; r < 4; ++r)
#pragma unroll
    for (int msk = 1; msk < 16; msk <<= 1) rs[r] += __shfl_xor(rs[r], msk);

  float relc[4][4] = {};
  if (SELF) {
#pragma unroll
    for (int r = 0; r < 4; ++r) {
      int lrow = l0 + 4 * g + r;
      for (int rr = 0; rr < 64; ++rr) {
        float bw = buck[lrow * 64 + rr];
#pragma unroll
        for (int df = 0; df < 4; ++df) relc[r][df] += bw * rv_s[rr * 64 + df * 16 + li];
      }
    }
  }
#pragma unroll
  for (int df = 0; df < 4; ++df) {
#pragma unroll
    for (int r = 0; r < 4; ++r) {
      float v = oacc[df][r];
      if (SELF) v += relc[r][df];
      v /= rs[r];
      att[(size_t)(rowq0 + l0 + 4 * g + r) * Hc + h * 64 + df * 16 + li] = f2bf(v);
    }
  }
}

// ---------------------------------------------------------------------------
// out = LayerNorm(x + dlt) * g + b ; also writes bf16 copy
// ---------------------------------------------------------------------------
__global__ __launch_bounds__(256) void ln_res(
    const float* __restrict__ x, const float* __restrict__ dlt,
    const float* __restrict__ g, const float* __restrict__ bta,
    float* __restrict__ out, u16* __restrict__ obf) {
  __shared__ float red_s[256];
  const int row = blockIdx.x, tid = threadIdx.x;
  const size_t base = (size_t)row * Hc;
  float v0 = x[base + tid] + dlt[base + tid];
  float v1 = x[base + tid + 256] + dlt[base + tid + 256];

  red_s[tid] = v0 + v1;
  __syncthreads();
  for (int s = 128; s > 0; s >>= 1) {
    if (tid < s) red_s[tid] += red_s[tid + s];
    __syncthreads();
  }
  const float mean = red_s[0] * (1.f / Hc);
  __syncthreads();
  const float d0 = v0 - mean, d1 = v1 - mean;
  red_s[tid] = d0 * d0 + d1 * d1;
  __syncthreads();
  for (int s = 128; s > 0; s >>= 1) {
    if (tid < s) red_s[tid] += red_s[tid + s];
    __syncthreads();
  }
  const float rstd = rsqrtf(red_s[0] * (1.f / Hc) + EPSV);
  float o0 = d0 * rstd * g[tid] + bta[tid];
  float o1 = d1 * rstd * g[tid + 256] + bta[tid + 256];
  out[base + tid] = o0;
  out[base + tid + 256] = o1;
  obf[base + tid] = f2bf(o0);
  obf[base + tid + 256] = f2bf(o1);
}

// ---------------------------------------------------------------------------
extern "C" void kernel_launch(void* const* d_in, const int* in_sizes, int n_in,
                              void* d_out, int out_size, void* d_ws, size_t ws_size,
                              hipStream_t stream) {
  const float* q    = (const float*)d_in[0];
  const float* kv   = (const float*)d_in[1];
  const float* relk = (const float*)d_in[2];
  const float* relv = (const float*)d_in[3];
  const float* Wq_s = (const float*)d_in[4];
  const float* bq_s = (const float*)d_in[5];
  const float* Wk_s = (const float*)d_in[6];
  const float* Wv_s = (const float*)d_in[7];
  const float* Wo_s = (const float*)d_in[8];
  const float* bo_s = (const float*)d_in[9];
  const float* ln1g = (const float*)d_in[10];
  const float* ln1b = (const float*)d_in[11];
  const float* Wq_c = (const float*)d_in[12];
  const float* bq_c = (const float*)d_in[13];
  const float* Wk_c = (const float*)d_in[14];
  const float* Wv_c = (const float*)d_in[15];
  const float* Wo_c = (const float*)d_in[16];
  const float* bo_c = (const float*)d_in[17];
  const float* ln2g = (const float*)d_in[18];
  const float* ln2b = (const float*)d_in[19];
  const float* W1   = (const float*)d_in[20];
  const float* b1   = (const float*)d_in[21];
  const float* W2   = (const float*)d_in[22];
  const float* b2   = (const float*)d_in[23];
  const float* ln3g = (const float*)d_in[24];
  const float* ln3b = (const float*)d_in[25];
  const int*   rel  = (const int*)d_in[26];

  char* ws = (char*)d_ws;
  const size_t NT = (size_t)Bc * Tc;  // 2048 token rows
  float* o    = (float*)ws;                       ws += NT * Hc * 4;   // 4MB
  float* bDlt = (float*)ws;                       ws += NT * Hc * 4;   // 4MB
  float* Qr   = (float*)ws;                       ws += NT * 8 * 64 * 4; // 4MB
  u16* obf    = (u16*)ws;                         ws += NT * Hc * 2;   // 2MB
  u16* kvbf   = (u16*)ws;                         ws += NT * Hc * 2;   // 2MB
  u16* bQKV   = (u16*)ws;                         ws += NT * 1536 * 2; // 6MB
  u16* bQc    = (u16*)ws;                         ws += NT * Hc * 2;   // 2MB
  u16* bKVc   = (u16*)ws;                         ws += NT * 2048 * 2; // 8MB
  u16* bAtt   = (u16*)ws;                         ws += NT * Hc * 2;   // 2MB
  u16* bH     = (u16*)ws;                         ws += NT * FFc * 2;  // 8MB
  u16* wbuf   = (u16*)ws;                         ws += (size_t)8388608 * 2; // 16MB

  // weight-buffer element offsets
  const size_t QKV0 = 0,       QKVsz = 786432;
  const size_t WO   = 1572864, WOsz  = 262144;
  const size_t QC   = 2097152;
  const size_t WOC  = 2621440;
  const size_t W1T  = 3145728, W1sz  = 1048576;
  const size_t W2T  = 5242880;
  const size_t KVC  = 7340032;

  WPtrs wp;
  wp.p[0] = Wq_s; wp.p[1] = Wk_s; wp.p[2] = Wv_s; wp.p[3] = Wo_s;
  wp.p[4] = Wq_c; wp.p[5] = Wk_c; wp.p[6] = Wv_c; wp.p[7] = Wo_c;
  wp.p[8] = W1;   wp.p[9] = W2;

  dim3 blk(256);
  wcvt<<<dim3(2048), blk, 0, stream>>>(wp, wbuf);
  acvt<<<dim3(1024), blk, 0, stream>>>(q, kv, obf, kvbf);
  hipMemcpyAsync(o, q, NT * Hc * 4, hipMemcpyDeviceToDevice, stream);

  // cross K/V for both layers: [2048 tok][2048] bf16
  gemm_mfma<128, false, 1><<<dim3(16, 16), blk, 0, stream>>>(
      kvbf, wbuf + KVC, nullptr, 0, bKVc, 2048, 512);

  const dim3 gA(8, 8, 4);    // attention: (qtile, head, batch)
  const dim3 gLN(NT);

  for (int i = 0; i < NLc; ++i) {
    // --- relation-aware masked self-attention ---
    gemm_mfma<128, false, 1><<<dim3(12, 16), blk, 0, stream>>>(
        obf, wbuf + QKV0 + i * QKVsz, bq_s + i * Hc, Hc, bQKV, 1536, 512);
    qr_kernel<<<dim3(4096), blk, 0, stream>>>(bQKV, relk, Qr);
    attn_mfma<true><<<gA, blk, 0, stream>>>(
        bQKV, 1536, bQKV + 512, bQKV + 1024, 1536, Qr, rel, relv, bAtt);
    gemm_mfma<64, false, 0><<<dim3(4, 32), blk, 0, stream>>>(
        bAtt, wbuf + WO + i * WOsz, bo_s + i * Hc, Hc, bDlt, Hc, 512);
    ln_res<<<gLN, blk, 0, stream>>>(o, bDlt, ln1g + i * Hc, ln1b + i * Hc, o, obf);

    // --- cross-attention ---
    gemm_mfma<64, false, 1><<<dim3(4, 32), blk, 0, stream>>>(
        obf, wbuf + QC + i * WOsz, bq_c + i * Hc, Hc, bQc, Hc, 512);
    attn_mfma<false><<<gA, blk, 0, stream>>>(
        bQc, 512, bKVc + i * 1024, bKVc + i * 1024 + 512, 2048,
        nullptr, nullptr, nullptr, bAtt);
    gemm_mfma<64, false, 0><<<dim3(4, 32), blk, 0, stream>>>(
        bAtt, wbuf + WOC + i * WOsz, bo_c + i * Hc, Hc, bDlt, Hc, 512);
    ln_res<<<gLN, blk, 0, stream>>>(o, bDlt, ln2g + i * Hc, ln2b + i * Hc, o, obf);

    // --- feedforward ---
    gemm_mfma<128, true, 1><<<dim3(16, 16), blk, 0, stream>>>(
        obf, wbuf + W1T + i * W1sz, b1 + i * FFc, FFc, bH, FFc, 512);
    gemm_mfma<64, false, 0><<<dim3(4, 32), blk, 0, stream>>>(
        bH, wbuf + W2T + i * W1sz, b2 + i * Hc, Hc, bDlt, Hc, 2048);
    float* lnout = (i == NLc - 1) ? (float*)d_out : o;
    ln_res<<<gLN, blk, 0, stream>>>(o, bDlt, ln3g + i * Hc, ln3b + i * Hc, lnout, obf);
  }
}

// Round 4
// 428.262 us; speedup vs baseline: 4.9715x; 1.1252x over previous
//
#include <hip/hip_runtime.h>

static constexpr int Hc  = 512;
static constexpr int NHc = 8;
static constexpr int DHc = 64;
static constexpr int NLc = 2;
static constexpr int Rc  = 64;
static constexpr int FFc = 2048;
static constexpr int Bc  = 4;
static constexpr int Tc  = 512;
#define NEGV (-1e10f)
#define EPSV 1e-5f
#define THRV 6.0f

typedef unsigned short u16;
typedef __attribute__((ext_vector_type(8))) short s16x8;
typedef __attribute__((ext_vector_type(4))) float f32x4;

__device__ __forceinline__ f32x4 mfma_bf16(s16x8 a, s16x8 b, f32x4 c) {
  return __builtin_amdgcn_mfma_f32_16x16x32_bf16(a, b, c, 0, 0, 0);
}
__device__ __forceinline__ u16 f2bf(float f) {
  union { float f; unsigned u; } x; x.f = f;
  unsigned r = (x.u + 0x7FFFu + ((x.u >> 16) & 1u)) >> 16;
  return (u16)r;
}
__device__ __forceinline__ float bf2f(u16 h) {
  union { unsigned u; float f; } x; x.u = ((unsigned)h) << 16;
  return x.f;
}
__device__ __forceinline__ unsigned cvtpk(float a, float b) {
  unsigned r;
  asm("v_cvt_pk_bf16_f32 %0, %1, %2" : "=v"(r) : "v"(a), "v"(b));
  return r;
}

// ---------------------------------------------------------------------------
// bf16 MFMA GEMM: C[M,N] = A[M,K] @ Wt[N,K]^T (+bias for col<biasN) (+relu)
// 256 threads, 4 waves (2x2). BK=32. LDS 16B-chunk XOR swizzle.
// ---------------------------------------------------------------------------
template <int BM, int BN, bool RELU, int OUT>  // OUT: 0=f32, 1=bf16
__global__ __launch_bounds__(256) void gemm_mfma(
    const u16* __restrict__ A, const u16* __restrict__ Wt,
    const float* __restrict__ bias, int biasN,
    void* __restrict__ Cout, int N, int K) {
  __shared__ u16 As[BM * 32];
  __shared__ u16 Bs[BN * 32];
  const int tid = threadIdx.x;
  const int w = tid >> 6, lane = tid & 63, g = lane >> 4, li = lane & 15;
  const int bn = blockIdx.x * BN, bm = blockIdx.y * BM;
  const int r0 = (w & 1) * (BM / 2), c0 = (w >> 1) * (BN / 2);
  constexpr int MR = BM / 32, NR = BN / 32;
  f32x4 acc[MR][NR];
#pragma unroll
  for (int i = 0; i < MR; ++i)
#pragma unroll
    for (int j = 0; j < NR; ++j) acc[i][j] = (f32x4){0.f, 0.f, 0.f, 0.f};

  for (int k0 = 0; k0 < K; k0 += 32) {
    __syncthreads();
#pragma unroll
    for (int it = 0; it < BM / 64; ++it) {
      int s = it * 256 + tid;
      int row = s >> 2, ch = s & 3;
      s16x8 v = *(const s16x8*)(A + (size_t)(bm + row) * K + k0 + ch * 8);
      *(s16x8*)&As[row * 32 + ((ch ^ (row & 3)) * 8)] = v;
    }
#pragma unroll
    for (int it = 0; it < BN / 64; ++it) {
      int s = it * 256 + tid;
      int row = s >> 2, ch = s & 3;
      s16x8 v = *(const s16x8*)(Wt + (size_t)(bn + row) * K + k0 + ch * 8);
      *(s16x8*)&Bs[row * 32 + ((ch ^ (row & 3)) * 8)] = v;
    }
    __syncthreads();
    s16x8 ar[MR], br[NR];
#pragma unroll
    for (int i = 0; i < MR; ++i) {
      int row = r0 + i * 16 + li;
      ar[i] = *(const s16x8*)&As[row * 32 + ((g ^ (row & 3)) * 8)];
    }
#pragma unroll
    for (int j = 0; j < NR; ++j) {
      int row = c0 + j * 16 + li;
      br[j] = *(const s16x8*)&Bs[row * 32 + ((g ^ (row & 3)) * 8)];
    }
#pragma unroll
    for (int i = 0; i < MR; ++i)
#pragma unroll
      for (int j = 0; j < NR; ++j) acc[i][j] = mfma_bf16(ar[i], br[j], acc[i][j]);
  }

#pragma unroll
  for (int j = 0; j < NR; ++j) {
    int col = bn + c0 + j * 16 + li;
    float bv = (bias && col < biasN) ? bias[col] : 0.f;
#pragma unroll
    for (int i = 0; i < MR; ++i) {
#pragma unroll
      for (int r = 0; r < 4; ++r) {
        int rowg = bm + r0 + i * 16 + 4 * g + r;
        float v = acc[i][j][r] + bv;
        if (RELU) v = fmaxf(v, 0.f);
        if (OUT == 0) ((float*)Cout)[(size_t)rowg * N + col] = v;
        else          ((u16*)Cout)[(size_t)rowg * N + col] = f2bf(v);
      }
    }
  }
}

// ---------------------------------------------------------------------------
// Weight transpose+convert: f32 [Ks][Ns] -> bf16 [Ns][Ks] at dstOff
// ---------------------------------------------------------------------------
struct WPtrs { const float* p[10]; };

__global__ __launch_bounds__(256) void wcvt(WPtrs wp, u16* __restrict__ dst) {
  constexpr int NE = 20;
  constexpr int srcIdx[NE] = {0,1,0,1,3,3,4,4,5,5,6,6,7,7,2,2,8,8,9,9};
  constexpr int srcOff[NE] = {0,0,262144,262144,0,262144,0,262144,0,262144,
                              0,262144,0,262144,0,262144,0,1048576,0,1048576};
  constexpr int dstOff[NE] = {0,262144,524288,786432,1048576,1310720,
                              1572864,1835008,2097152,2359296,2621440,2883584,
                              3145728,3407872,3670016,3932160,
                              4194304,5242880,6291456,7340032};
  constexpr int KsA[NE] = {512,512,512,512,512,512,512,512,512,512,
                           512,512,512,512,512,512,512,512,2048,2048};
  constexpr int NsA[NE] = {512,512,512,512,512,512,512,512,512,512,
                           512,512,512,512,512,512,2048,2048,512,512};
  constexpr int tileStart[NE] = {0,64,128,192,256,320,384,448,512,576,
                                 640,704,768,832,896,960,1024,1280,1536,1792};
  __shared__ float ts[64 * 65];
  const int tid = threadIdx.x;
  const int bid = blockIdx.x;
  int e = 0;
#pragma unroll
  for (int i = 1; i < NE; ++i) if (bid >= tileStart[i]) e = i;
  const int t = bid - tileStart[e];
  const int Ks_ = KsA[e], Ns_ = NsA[e];
  const int tn = t % (Ns_ >> 6), tk = t / (Ns_ >> 6);
  const float* src = wp.p[srcIdx[e]] + srcOff[e];

  {
    int r = tid >> 2, cb = (tid & 3) * 16;
    const float* sp = src + (size_t)(tk * 64 + r) * Ns_ + tn * 64 + cb;
#pragma unroll
    for (int j = 0; j < 4; ++j) {
      float4 v = ((const float4*)sp)[j];
      float* d = &ts[r * 65 + cb + j * 4];
      d[0] = v.x; d[1] = v.y; d[2] = v.z; d[3] = v.w;
    }
  }
  __syncthreads();
  {
    int n = tid >> 2, kb = (tid & 3) * 16;
    u16* dp = dst + dstOff[e] + (size_t)(tn * 64 + n) * Ks_ + tk * 64 + kb;
    s16x8 o0, o1;
#pragma unroll
    for (int j = 0; j < 8; ++j) o0[j] = (short)f2bf(ts[(kb + j) * 65 + n]);
#pragma unroll
    for (int j = 0; j < 8; ++j) o1[j] = (short)f2bf(ts[(kb + 8 + j) * 65 + n]);
    *(s16x8*)dp = o0;
    *(s16x8*)(dp + 8) = o1;
  }
}

// ---------------------------------------------------------------------------
// activations f32->bf16 (blocks 0..1023); block 1024: relv -> relv^T bf16
// ---------------------------------------------------------------------------
__global__ __launch_bounds__(256) void acvt(
    const float* __restrict__ q, const float* __restrict__ kv,
    const float* __restrict__ relv,
    u16* __restrict__ obf, u16* __restrict__ kvbf, u16* __restrict__ relvt) {
  int bid = blockIdx.x, tid = threadIdx.x;
  if (bid == 1024) {
    int d = tid >> 2, rb = (tid & 3) * 16;
    s16x8 o0, o1;
#pragma unroll
    for (int j = 0; j < 8; ++j) o0[j] = (short)f2bf(relv[(rb + j) * 64 + d]);
#pragma unroll
    for (int j = 0; j < 8; ++j) o1[j] = (short)f2bf(relv[(rb + 8 + j) * 64 + d]);
    *(s16x8*)(relvt + d * 64 + rb) = o0;
    *(s16x8*)(relvt + d * 64 + rb + 8) = o1;
    return;
  }
  int i = bid * 256 + tid;
  const float* src; u16* dst; size_t off;
  if (i < 131072) { src = q; dst = obf; off = (size_t)i * 8; }
  else { src = kv; dst = kvbf; off = (size_t)(i - 131072) * 8; }
  float4 a = *(const float4*)(src + off);
  float4 b = *(const float4*)(src + off + 4);
  s16x8 o;
  o[0] = (short)f2bf(a.x); o[1] = (short)f2bf(a.y);
  o[2] = (short)f2bf(a.z); o[3] = (short)f2bf(a.w);
  o[4] = (short)f2bf(b.x); o[5] = (short)f2bf(b.y);
  o[6] = (short)f2bf(b.z); o[7] = (short)f2bf(b.w);
  *(s16x8*)(dst + off) = o;
}

// ---------------------------------------------------------------------------
// Qr[(row*8+h), r] = sum_d Q[row, h*64+d] * relk[r, d]  (Q = bQK, stride 1024)
// ---------------------------------------------------------------------------
__global__ __launch_bounds__(256) void qr_kernel(
    const u16* __restrict__ Q, const float* __restrict__ relk,
    float* __restrict__ Qr) {
  __shared__ float rk[64 * 65];
  __shared__ float qs[4][64];
  const int tid = threadIdx.x;
  {
    int r = tid >> 2, cb = (tid & 3) * 16;
    const float* sp = relk + r * 64 + cb;
#pragma unroll
    for (int j = 0; j < 4; ++j) {
      float4 v = ((const float4*)sp)[j];
      float* d = &rk[r * 65 + cb + j * 4];
      d[0] = v.x; d[1] = v.y; d[2] = v.z; d[3] = v.w;
    }
  }
  const int sub = tid >> 6, r = tid & 63;
  const int unit = blockIdx.x * 4 + sub;  // unit = row*8 + h
  qs[sub][r] = bf2f(Q[(size_t)(unit >> 3) * 1024 + (unit & 7) * 64 + r]);
  __syncthreads();
  float acc = 0.f;
#pragma unroll
  for (int d = 0; d < 64; ++d) acc += qs[sub][d] * rk[r * 65 + d];
  Qr[(size_t)unit * 64 + r] = acc;
}

// ---------------------------------------------------------------------------
// Relation-aware masked self-attention. 128 thr (2 waves x 16 q-rows).
// Swapped QK (lane owns q-row tl=w*16+li), online softmax, causal chunk skip,
// in-register P via cvt_pk+shfl, rel-V via bucket LDS + MFMA vs relv^T.
// Grid: (16 qtile32, 8 head, 4 batch)
// ---------------------------------------------------------------------------
__global__ __launch_bounds__(128) void attn_self(
    const u16* __restrict__ Qb, const u16* __restrict__ Kb,  // stride 1024
    const u16* __restrict__ VT,                              // [512][2048]
    const float* __restrict__ Qr, const int* __restrict__ rel_ids,
    const u16* __restrict__ relvt, u16* __restrict__ att) {
  __shared__ u16 Ks[64 * 64];
  __shared__ u16 Vts[64 * 64];
  __shared__ unsigned char rel8[32 * 68];
  __shared__ float qrs[32 * 66];
  __shared__ float buck[32 * 66];
  __shared__ int anymask;

  const int tid = threadIdx.x;
  const int w = tid >> 6, lane = tid & 63, g = lane >> 4, li = lane & 15;
  const int tl = w * 16 + li;               // tile-local q-row this lane owns
  const int qt = blockIdx.x, h = blockIdx.y, b = blockIdx.z;
  const int lrow = qt * 32 + tl;            // row within batch
  const int growq = b * 512 + qt * 32;      // first global row of tile
  const int c_hi = qt >> 1;
  if (tid == 0) anymask = 0;

  s16x8 aq0 = *(const s16x8*)(Qb + (size_t)(b * 512 + lrow) * 1024 + h * 64 + g * 8);
  s16x8 aq1 = *(const s16x8*)(Qb + (size_t)(b * 512 + lrow) * 1024 + h * 64 + 32 + g * 8);

#pragma unroll
  for (int j = 0; j < 8; ++j) {  // stage Qr rows + zero buckets
    int slot = j * 128 + tid;
    int row = slot >> 5, x2 = (slot & 31) * 2;
    float2 v = *(const float2*)(Qr + ((size_t)(growq + row) * 8 + h) * 64 + x2);
    *(float2*)&qrs[row * 66 + x2] = v;
    *(float2*)&buck[row * 66 + x2] = make_float2(0.f, 0.f);
  }

  float mrow = NEGV, rsum = 0.f;
  f32x4 oacc[4];
#pragma unroll
  for (int d = 0; d < 4; ++d) oacc[d] = (f32x4){0.f, 0.f, 0.f, 0.f};

  for (int c8 = 0; c8 <= c_hi; ++c8) {
    __syncthreads();
#pragma unroll
    for (int c = 0; c < 4; ++c) {  // stage K and V^T (vector, swizzled)
      int m = c * 16 + (tid >> 3), ch = tid & 7;
      *(s16x8*)&Ks[m * 64 + ((ch ^ (m & 7)) * 8)] =
          *(const s16x8*)(Kb + (size_t)(b * 512 + c8 * 64 + m) * 1024 + h * 64 + ch * 8);
      *(s16x8*)&Vts[m * 64 + ((ch ^ (m & 7)) * 8)] =
          *(const s16x8*)(VT + (size_t)(h * 64 + m) * 2048 + b * 512 + c8 * 64 + ch * 8);
    }
#pragma unroll
    for (int c = 0; c < 4; ++c) {  // stage rel ids as bytes (pitch 68)
      int slot = c * 128 + tid;
      int row = slot >> 4, xi = slot & 15;
      int4 rv = *(const int4*)(rel_ids + (size_t)(growq + row) * 512 + c8 * 64 + xi * 4);
      unsigned pk8 = (unsigned)(rv.x & 255) | ((unsigned)(rv.y & 255) << 8) |
                     ((unsigned)(rv.z & 255) << 16) | ((unsigned)(rv.w & 255) << 24);
      ((unsigned*)rel8)[row * 17 + xi] = pk8;
    }
    __syncthreads();

    f32x4 sf[4];
#pragma unroll
    for (int mt = 0; mt < 4; ++mt) {  // S^T = K @ Q^T
      sf[mt] = (f32x4){0.f, 0.f, 0.f, 0.f};
      int row = mt * 16 + li;
      s16x8 ak0 = *(const s16x8*)&Ks[row * 64 + ((g ^ (row & 7)) * 8)];
      s16x8 ak1 = *(const s16x8*)&Ks[row * 64 + (((4 + g) ^ (row & 7)) * 8)];
      sf[mt] = mfma_bf16(ak0, aq0, sf[mt]);
      sf[mt] = mfma_bf16(ak1, aq1, sf[mt]);
    }
    float p[4][4];
    int rl[4][4];
    float pmax = NEGV;
#pragma unroll
    for (int mt = 0; mt < 4; ++mt) {
      unsigned rw = *(const unsigned*)&rel8[tl * 68 + mt * 16 + 4 * g];
#pragma unroll
      for (int r = 0; r < 4; ++r) {
        int mm = mt * 16 + 4 * g + r;
        int rel = (rw >> (8 * r)) & 255;
        rl[mt][r] = rel;
        bool valid = (rel != 0) && (c8 * 64 + mm <= lrow);
        p[mt][r] = valid ? (sf[mt][r] + qrs[tl * 66 + rel]) * 0.125f : NEGV;
        pmax = fmaxf(pmax, p[mt][r]);
      }
    }
    pmax = fmaxf(pmax, __shfl_xor(pmax, 16));
    pmax = fmaxf(pmax, __shfl_xor(pmax, 32));
    if (__any(pmax > mrow + THRV)) {  // online rescale (deferred)
      float mnew = (pmax > mrow + THRV) ? pmax : mrow;
      float f = __expf(mrow - mnew);
      rsum *= f;
#pragma unroll
      for (int j = 0; j < 8; ++j) {
        float2* p2 = (float2*)&buck[tl * 66 + g * 16 + 2 * j];
        float2 v = *p2; v.x *= f; v.y *= f; *p2 = v;
      }
#pragma unroll
      for (int r = 0; r < 4; ++r) {
        float fr = __shfl(f, 4 * g + r);
#pragma unroll
        for (int df = 0; df < 4; ++df) oacc[df][r] *= fr;
      }
      mrow = mnew;
    }
    unsigned pk[4][2];
#pragma unroll
    for (int mt = 0; mt < 4; ++mt) {
#pragma unroll
      for (int r = 0; r < 4; ++r) {
        float pv = __expf(p[mt][r] - mrow);
        p[mt][r] = pv;
        rsum += pv;
        if (pv > 0.f) atomicAdd(&buck[tl * 66 + rl[mt][r]], pv);
      }
      pk[mt][0] = cvtpk(p[mt][0], p[mt][1]);
      pk[mt][1] = cvtpk(p[mt][2], p[mt][3]);
    }
#pragma unroll
    for (int kk = 0; kk < 2; ++kk) {  // assemble P row-fragments + PV
      union { s16x8 v; unsigned u[4]; } pa;
#pragma unroll
      for (int q = 0; q < 4; ++q) {
        int src = ((2 * (g & 1) + (q >> 1)) << 4) + li;
        unsigned uA = __shfl(pk[2 * kk][q & 1], src);
        unsigned uB = __shfl(pk[2 * kk + 1][q & 1], src);
        pa.u[q] = (g < 2) ? uA : uB;
      }
#pragma unroll
      for (int df = 0; df < 4; ++df) {
        int row = df * 16 + li;
        s16x8 bv = *(const s16x8*)&Vts[row * 64 + (((kk * 4 + g) ^ (row & 7)) * 8)];
        oacc[df] = mfma_bf16(pa.v, bv, oacc[df]);
      }
    }
  }

  // fully-masked-row continuation (rare): uniform weights over remaining cols
  if (__any(mrow == NEGV) && lane == 0) anymask = 1;
  __syncthreads();
  if (anymask) {
    float pm = (mrow == NEGV) ? 1.f : 0.f;
    union { s16x8 v; unsigned u[4]; } pa;
    unsigned pku = cvtpk(pm, pm);
#pragma unroll
    for (int q = 0; q < 4; ++q) pa.u[q] = pku;
    for (int c8 = c_hi + 1; c8 < 8; ++c8) {
      __syncthreads();
#pragma unroll
      for (int c = 0; c < 4; ++c) {
        int m = c * 16 + (tid >> 3), ch = tid & 7;
        *(s16x8*)&Vts[m * 64 + ((ch ^ (m & 7)) * 8)] =
            *(const s16x8*)(VT + (size_t)(h * 64 + m) * 2048 + b * 512 + c8 * 64 + ch * 8);
      }
#pragma unroll
      for (int c = 0; c < 4; ++c) {
        int slot = c * 128 + tid;
        int row = slot >> 4, xi = slot & 15;
        int4 rv = *(const int4*)(rel_ids + (size_t)(growq + row) * 512 + c8 * 64 + xi * 4);
        unsigned pk8 = (unsigned)(rv.x & 255) | ((unsigned)(rv.y & 255) << 8) |
                       ((unsigned)(rv.z & 255) << 16) | ((unsigned)(rv.w & 255) << 24);
        ((unsigned*)rel8)[row * 17 + xi] = pk8;
      }
      __syncthreads();
      if (pm > 0.f) {
        rsum += 16.f;
#pragma unroll
        for (int mt = 0; mt < 4; ++mt) {
          unsigned rw = *(const unsigned*)&rel8[tl * 68 + mt * 16 + 4 * g];
#pragma unroll
          for (int r = 0; r < 4; ++r)
            atomicAdd(&buck[tl * 66 + ((rw >> (8 * r)) & 255)], 1.f);
        }
      }
#pragma unroll
      for (int kk = 0; kk < 2; ++kk)
#pragma unroll
        for (int df = 0; df < 4; ++df) {
          int row = df * 16 + li;
          s16x8 bv = *(const s16x8*)&Vts[row * 64 + (((kk * 4 + g) ^ (row & 7)) * 8)];
          oacc[df] = mfma_bf16(pa.v, bv, oacc[df]);
        }
    }
  }

  rsum += __shfl_xor(rsum, 16);
  rsum += __shfl_xor(rsum, 32);

  // rel-V: oacc += buck @ relv  (A = buck rows, B = relv^T)
#pragma unroll
  for (int kk = 0; kk < 2; ++kk) {
    float bb[8];
#pragma unroll
    for (int j = 0; j < 4; ++j) {
      float2 v = *(const float2*)&buck[tl * 66 + kk * 32 + g * 8 + 2 * j];
      bb[2 * j] = v.x; bb[2 * j + 1] = v.y;
    }
    union { s16x8 v; unsigned u[4]; } pb;
#pragma unroll
    for (int q = 0; q < 4; ++q) pb.u[q] = cvtpk(bb[2 * q], bb[2 * q + 1]);
#pragma unroll
    for (int df = 0; df < 4; ++df) {
      s16x8 rb = *(const s16x8*)(relvt + (df * 16 + li) * 64 + kk * 32 + g * 8);
      oacc[df] = mfma_bf16(pb.v, rb, oacc[df]);
    }
  }

  float inv[4];
#pragma unroll
  for (int r = 0; r < 4; ++r) inv[r] = 1.f / __shfl(rsum, 4 * g + r);
#pragma unroll
  for (int df = 0; df < 4; ++df)
#pragma unroll
    for (int r = 0; r < 4; ++r)
      att[(size_t)(growq + w * 16 + 4 * g + r) * 512 + h * 64 + df * 16 + li] =
          f2bf(oacc[df][r] * inv[r]);
}

// ---------------------------------------------------------------------------
// Cross-attention (no mask): 256 thr (4 waves x 16 q-rows), online softmax.
// Grid: (8 qtile64, 8 head, 4 batch)
// ---------------------------------------------------------------------------
__global__ __launch_bounds__(256) void attn_cross(
    const u16* __restrict__ Qb,   // stride 512
    const u16* __restrict__ Kb,   // stride 1024
    const u16* __restrict__ VT,   // stride 2048
    u16* __restrict__ att) {
  __shared__ u16 Ks[64 * 64];
  __shared__ u16 Vts[64 * 64];
  const int tid = threadIdx.x;
  const int w = tid >> 6, lane = tid & 63, g = lane >> 4, li = lane & 15;
  const int qt = blockIdx.x, h = blockIdx.y, b = blockIdx.z;
  const int lrow = qt * 64 + w * 16 + li;

  s16x8 aq0 = *(const s16x8*)(Qb + (size_t)(b * 512 + lrow) * 512 + h * 64 + g * 8);
  s16x8 aq1 = *(const s16x8*)(Qb + (size_t)(b * 512 + lrow) * 512 + h * 64 + 32 + g * 8);

  float mrow = NEGV, rsum = 0.f;
  f32x4 oacc[4];
#pragma unroll
  for (int d = 0; d < 4; ++d) oacc[d] = (f32x4){0.f, 0.f, 0.f, 0.f};

  for (int c8 = 0; c8 < 8; ++c8) {
    __syncthreads();
#pragma unroll
    for (int c = 0; c < 2; ++c) {
      int m = c * 32 + (tid >> 3), ch = tid & 7;
      *(s16x8*)&Ks[m * 64 + ((ch ^ (m & 7)) * 8)] =
          *(const s16x8*)(Kb + (size_t)(b * 512 + c8 * 64 + m) * 1024 + h * 64 + ch * 8);
      *(s16x8*)&Vts[m * 64 + ((ch ^ (m & 7)) * 8)] =
          *(const s16x8*)(VT + (size_t)(h * 64 + m) * 2048 + b * 512 + c8 * 64 + ch * 8);
    }
    __syncthreads();

    f32x4 sf[4];
#pragma unroll
    for (int mt = 0; mt < 4; ++mt) {
      sf[mt] = (f32x4){0.f, 0.f, 0.f, 0.f};
      int row = mt * 16 + li;
      s16x8 ak0 = *(const s16x8*)&Ks[row * 64 + ((g ^ (row & 7)) * 8)];
      s16x8 ak1 = *(const s16x8*)&Ks[row * 64 + (((4 + g) ^ (row & 7)) * 8)];
      sf[mt] = mfma_bf16(ak0, aq0, sf[mt]);
      sf[mt] = mfma_bf16(ak1, aq1, sf[mt]);
    }
    float p[4][4];
    float pmax = NEGV;
#pragma unroll
    for (int mt = 0; mt < 4; ++mt)
#pragma unroll
      for (int r = 0; r < 4; ++r) {
        p[mt][r] = sf[mt][r] * 0.125f;
        pmax = fmaxf(pmax, p[mt][r]);
      }
    pmax = fmaxf(pmax, __shfl_xor(pmax, 16));
    pmax = fmaxf(pmax, __shfl_xor(pmax, 32));
    if (__any(pmax > mrow + THRV)) {
      float mnew = (pmax > mrow + THRV) ? pmax : mrow;
      float f = __expf(mrow - mnew);
      rsum *= f;
#pragma unroll
      for (int r = 0; r < 4; ++r) {
        float fr = __shfl(f, 4 * g + r);
#pragma unroll
        for (int df = 0; df < 4; ++df) oacc[df][r] *= fr;
      }
      mrow = mnew;
    }
    unsigned pk[4][2];
#pragma unroll
    for (int mt = 0; mt < 4; ++mt) {
#pragma unroll
      for (int r = 0; r < 4; ++r) {
        float pv = __expf(p[mt][r] - mrow);
        p[mt][r] = pv;
        rsum += pv;
      }
      pk[mt][0] = cvtpk(p[mt][0], p[mt][1]);
      pk[mt][1] = cvtpk(p[mt][2], p[mt][3]);
    }
#pragma unroll
    for (int kk = 0; kk < 2; ++kk) {
      union { s16x8 v; unsigned u[4]; } pa;
#pragma unroll
      for (int q = 0; q < 4; ++q) {
        int src = ((2 * (g & 1) + (q >> 1)) << 4) + li;
        unsigned uA = __shfl(pk[2 * kk][q & 1], src);
        unsigned uB = __shfl(pk[2 * kk + 1][q & 1], src);
        pa.u[q] = (g < 2) ? uA : uB;
      }
#pragma unroll
      for (int df = 0; df < 4; ++df) {
        int row = df * 16 + li;
        s16x8 bv = *(const s16x8*)&Vts[row * 64 + (((kk * 4 + g) ^ (row & 7)) * 8)];
        oacc[df] = mfma_bf16(pa.v, bv, oacc[df]);
      }
    }
  }

  rsum += __shfl_xor(rsum, 16);
  rsum += __shfl_xor(rsum, 32);
  float inv[4];
#pragma unroll
  for (int r = 0; r < 4; ++r) inv[r] = 1.f / __shfl(rsum, 4 * g + r);
#pragma unroll
  for (int df = 0; df < 4; ++df)
#pragma unroll
    for (int r = 0; r < 4; ++r)
      att[(size_t)(b * 512 + qt * 64 + w * 16 + 4 * g + r) * 512 + h * 64 + df * 16 + li] =
          f2bf(oacc[df][r] * inv[r]);
}

// ---------------------------------------------------------------------------
// out = LayerNorm(x + dlt) * g + b ; also writes bf16 copy
// ---------------------------------------------------------------------------
__global__ __launch_bounds__(256) void ln_res(
    const float* __restrict__ x, const float* __restrict__ dlt,
    const float* __restrict__ g, const float* __restrict__ bta,
    float* __restrict__ out, u16* __restrict__ obf) {
  __shared__ float red_s[256];
  const int row = blockIdx.x, tid = threadIdx.x;
  const size_t base = (size_t)row * Hc;
  float v0 = x[base + tid] + dlt[base + tid];
  float v1 = x[base + tid + 256] + dlt[base + tid + 256];

  red_s[tid] = v0 + v1;
  __syncthreads();
  for (int s = 128; s > 0; s >>= 1) {
    if (tid < s) red_s[tid] += red_s[tid + s];
    __syncthreads();
  }
  const float mean = red_s[0] * (1.f / Hc);
  __syncthreads();
  const float d0 = v0 - mean, d1 = v1 - mean;
  red_s[tid] = d0 * d0 + d1 * d1;
  __syncthreads();
  for (int s = 128; s > 0; s >>= 1) {
    if (tid < s) red_s[tid] += red_s[tid + s];
    __syncthreads();
  }
  const float rstd = rsqrtf(red_s[0] * (1.f / Hc) + EPSV);
  float o0 = d0 * rstd * g[tid] + bta[tid];
  float o1 = d1 * rstd * g[tid + 256] + bta[tid + 256];
  out[base + tid] = o0;
  out[base + tid + 256] = o1;
  obf[base + tid] = f2bf(o0);
  obf[base + tid + 256] = f2bf(o1);
}

// ---------------------------------------------------------------------------
extern "C" void kernel_launch(void* const* d_in, const int* in_sizes, int n_in,
                              void* d_out, int out_size, void* d_ws, size_t ws_size,
                              hipStream_t stream) {
  const float* q    = (const float*)d_in[0];
  const float* kv   = (const float*)d_in[1];
  const float* relk = (const float*)d_in[2];
  const float* relv = (const float*)d_in[3];
  const float* Wq_s = (const float*)d_in[4];
  const float* bq_s = (const float*)d_in[5];
  const float* Wk_s = (const float*)d_in[6];
  const float* Wv_s = (const float*)d_in[7];
  const float* Wo_s = (const float*)d_in[8];
  const float* bo_s = (const float*)d_in[9];
  const float* ln1g = (const float*)d_in[10];
  const float* ln1b = (const float*)d_in[11];
  const float* Wq_c = (const float*)d_in[12];
  const float* bq_c = (const float*)d_in[13];
  const float* Wk_c = (const float*)d_in[14];
  const float* Wv_c = (const float*)d_in[15];
  const float* Wo_c = (const float*)d_in[16];
  const float* bo_c = (const float*)d_in[17];
  const float* ln2g = (const float*)d_in[18];
  const float* ln2b = (const float*)d_in[19];
  const float* W1   = (const float*)d_in[20];
  const float* b1   = (const float*)d_in[21];
  const float* W2   = (const float*)d_in[22];
  const float* b2   = (const float*)d_in[23];
  const float* ln3g = (const float*)d_in[24];
  const float* ln3b = (const float*)d_in[25];
  const int*   rel  = (const int*)d_in[26];

  char* wsb = (char*)d_ws;
  const size_t NT = (size_t)Bc * Tc;  // 2048 token rows
  float* o     = (float*)wsb;  wsb += NT * Hc * 4;       // 4MB
  float* bDlt  = (float*)wsb;  wsb += NT * Hc * 4;       // 4MB
  float* Qr    = (float*)wsb;  wsb += NT * 8 * 64 * 4;   // 4MB
  u16* obf     = (u16*)wsb;    wsb += NT * Hc * 2;       // 2MB
  u16* kvbf    = (u16*)wsb;    wsb += NT * Hc * 2;       // 2MB
  u16* bQK     = (u16*)wsb;    wsb += NT * 1024 * 2;     // 4MB
  u16* bVt     = (u16*)wsb;    wsb += (size_t)512 * 2048 * 2;   // 2MB
  u16* bQc     = (u16*)wsb;    wsb += NT * Hc * 2;       // 2MB
  u16* bKc     = (u16*)wsb;    wsb += NT * 1024 * 2;     // 4MB
  u16* bVtc    = (u16*)wsb;    wsb += (size_t)1024 * 2048 * 2;  // 4MB
  u16* bAtt    = (u16*)wsb;    wsb += NT * Hc * 2;       // 2MB
  u16* bH      = (u16*)wsb;    wsb += NT * FFc * 2;      // 8MB
  u16* relvt   = (u16*)wsb;    wsb += 64 * 64 * 2;       // 8KB
  u16* wbuf    = (u16*)wsb;    wsb += (size_t)8388608 * 2;  // 16MB

  WPtrs wp;
  wp.p[0] = Wq_s; wp.p[1] = Wk_s; wp.p[2] = Wv_s; wp.p[3] = Wo_s;
  wp.p[4] = Wq_c; wp.p[5] = Wk_c; wp.p[6] = Wv_c; wp.p[7] = Wo_c;
  wp.p[8] = W1;   wp.p[9] = W2;

  dim3 blk(256);
  wcvt<<<dim3(2048), blk, 0, stream>>>(wp, wbuf);
  acvt<<<dim3(1025), blk, 0, stream>>>(q, kv, relv, obf, kvbf, relvt);
  hipMemcpyAsync(o, q, NT * Hc * 4, hipMemcpyDeviceToDevice, stream);

  // cross K (both layers) and cross V^T (both layers)
  gemm_mfma<64, 128, false, 1><<<dim3(8, 32), blk, 0, stream>>>(
      kvbf, wbuf + 2097152, nullptr, 0, bKc, 1024, 512);
  gemm_mfma<64, 128, false, 1><<<dim3(16, 16), blk, 0, stream>>>(
      wbuf + 2621440, kvbf, nullptr, 0, bVtc, 2048, 512);

  const dim3 gLN(NT);
  for (int i = 0; i < NLc; ++i) {
    // --- relation-aware masked self-attention ---
    gemm_mfma<64, 128, false, 1><<<dim3(8, 32), blk, 0, stream>>>(
        obf, wbuf + (size_t)i * 524288, bq_s + i * Hc, Hc, bQK, 1024, 512);
    gemm_mfma<64, 64, false, 1><<<dim3(32, 8), blk, 0, stream>>>(
        wbuf + 3670016 + (size_t)i * 262144, obf, nullptr, 0, bVt, 2048, 512);
    qr_kernel<<<dim3(4096), blk, 0, stream>>>(bQK, relk, Qr);
    attn_self<<<dim3(16, 8, 4), dim3(128), 0, stream>>>(
        bQK, bQK + 512, bVt, Qr, rel, relvt, bAtt);
    gemm_mfma<64, 64, false, 0><<<dim3(8, 32), blk, 0, stream>>>(
        bAtt, wbuf + 1048576 + (size_t)i * 262144, bo_s + i * Hc, Hc, bDlt, Hc, 512);
    ln_res<<<gLN, blk, 0, stream>>>(o, bDlt, ln1g + i * Hc, ln1b + i * Hc, o, obf);

    // --- cross-attention ---
    gemm_mfma<64, 64, false, 1><<<dim3(8, 32), blk, 0, stream>>>(
        obf, wbuf + 1572864 + (size_t)i * 262144, bq_c + i * Hc, Hc, bQc, Hc, 512);
    attn_cross<<<dim3(8, 8, 4), blk, 0, stream>>>(
        bQc, bKc + i * 512, bVtc + (size_t)i * 512 * 2048, bAtt);
    gemm_mfma<64, 64, false, 0><<<dim3(8, 32), blk, 0, stream>>>(
        bAtt, wbuf + 3145728 + (size_t)i * 262144, bo_c + i * Hc, Hc, bDlt, Hc, 512);
    ln_res<<<gLN, blk, 0, stream>>>(o, bDlt, ln2g + i * Hc, ln2b + i * Hc, o, obf);

    // --- feedforward ---
    gemm_mfma<128, 128, true, 1><<<dim3(16, 16), blk, 0, stream>>>(
        obf, wbuf + 4194304 + (size_t)i * 1048576, b1 + i * FFc, FFc, bH, FFc, 512);
    gemm_mfma<64, 64, false, 0><<<dim3(8, 32), blk, 0, stream>>>(
        bH, wbuf + 6291456 + (size_t)i * 1048576, b2 + i * Hc, Hc, bDlt, Hc, 2048);
    float* lnout = (i == NLc - 1) ? (float*)d_out : o;
    ln_res<<<gLN, blk, 0, stream>>>(o, bDlt, ln3g + i * Hc, ln3b + i * Hc, lnout, obf);
  }
}

// Round 5
// 425.980 us; speedup vs baseline: 4.9981x; 1.0054x over previous
//
#include <hip/hip_runtime.h>

static constexpr int Hc  = 512;
static constexpr int NHc = 8;
static constexpr int DHc = 64;
static constexpr int NLc = 2;
static constexpr int Rc  = 64;
static constexpr int FFc = 2048;
static constexpr int Bc  = 4;
static constexpr int Tc  = 512;
#define NEGV (-1e10f)
#define EPSV 1e-5f
#define THRV 6.0f

typedef unsigned short u16;
typedef __attribute__((ext_vector_type(8))) short s16x8;
typedef __attribute__((ext_vector_type(4))) float f32x4;

__device__ __forceinline__ f32x4 mfma_bf16(s16x8 a, s16x8 b, f32x4 c) {
  return __builtin_amdgcn_mfma_f32_16x16x32_bf16(a, b, c, 0, 0, 0);
}
__device__ __forceinline__ u16 f2bf(float f) {
  union { float f; unsigned u; } x; x.f = f;
  unsigned r = (x.u + 0x7FFFu + ((x.u >> 16) & 1u)) >> 16;
  return (u16)r;
}
__device__ __forceinline__ float bf2f(u16 h) {
  union { unsigned u; float f; } x; x.u = ((unsigned)h) << 16;
  return x.f;
}
__device__ __forceinline__ unsigned cvtpk(float a, float b) {
  unsigned r;
  asm("v_cvt_pk_bf16_f32 %0, %1, %2" : "=v"(r) : "v"(a), "v"(b));
  return r;
}

// ---------------------------------------------------------------------------
// bf16 MFMA GEMM: C[M,N] = A[M,K] @ Wt[N,K]^T (+bias for col<biasN) (+relu)
// 256 threads, 4 waves (2x2). BK=32. LDS 16B-chunk XOR swizzle.
// ---------------------------------------------------------------------------
template <int BM, int BN, bool RELU, int OUT>  // OUT: 0=f32, 1=bf16
__global__ __launch_bounds__(256) void gemm_mfma(
    const u16* __restrict__ A, const u16* __restrict__ Wt,
    const float* __restrict__ bias, int biasN,
    void* __restrict__ Cout, int N, int K) {
  __shared__ u16 As[BM * 32];
  __shared__ u16 Bs[BN * 32];
  const int tid = threadIdx.x;
  const int w = tid >> 6, lane = tid & 63, g = lane >> 4, li = lane & 15;
  const int bn = blockIdx.x * BN, bm = blockIdx.y * BM;
  const int r0 = (w & 1) * (BM / 2), c0 = (w >> 1) * (BN / 2);
  constexpr int MR = BM / 32, NR = BN / 32;
  f32x4 acc[MR][NR];
#pragma unroll
  for (int i = 0; i < MR; ++i)
#pragma unroll
    for (int j = 0; j < NR; ++j) acc[i][j] = (f32x4){0.f, 0.f, 0.f, 0.f};

  for (int k0 = 0; k0 < K; k0 += 32) {
    __syncthreads();
#pragma unroll
    for (int it = 0; it < BM / 64; ++it) {
      int s = it * 256 + tid;
      int row = s >> 2, ch = s & 3;
      s16x8 v = *(const s16x8*)(A + (size_t)(bm + row) * K + k0 + ch * 8);
      *(s16x8*)&As[row * 32 + ((ch ^ (row & 3)) * 8)] = v;
    }
#pragma unroll
    for (int it = 0; it < BN / 64; ++it) {
      int s = it * 256 + tid;
      int row = s >> 2, ch = s & 3;
      s16x8 v = *(const s16x8*)(Wt + (size_t)(bn + row) * K + k0 + ch * 8);
      *(s16x8*)&Bs[row * 32 + ((ch ^ (row & 3)) * 8)] = v;
    }
    __syncthreads();
    s16x8 ar[MR], br[NR];
#pragma unroll
    for (int i = 0; i < MR; ++i) {
      int row = r0 + i * 16 + li;
      ar[i] = *(const s16x8*)&As[row * 32 + ((g ^ (row & 3)) * 8)];
    }
#pragma unroll
    for (int j = 0; j < NR; ++j) {
      int row = c0 + j * 16 + li;
      br[j] = *(const s16x8*)&Bs[row * 32 + ((g ^ (row & 3)) * 8)];
    }
#pragma unroll
    for (int i = 0; i < MR; ++i)
#pragma unroll
      for (int j = 0; j < NR; ++j) acc[i][j] = mfma_bf16(ar[i], br[j], acc[i][j]);
  }

#pragma unroll
  for (int j = 0; j < NR; ++j) {
    int col = bn + c0 + j * 16 + li;
    float bv = (bias && col < biasN) ? bias[col] : 0.f;
#pragma unroll
    for (int i = 0; i < MR; ++i) {
#pragma unroll
      for (int r = 0; r < 4; ++r) {
        int rowg = bm + r0 + i * 16 + 4 * g + r;
        float v = acc[i][j][r] + bv;
        if (RELU) v = fmaxf(v, 0.f);
        if (OUT == 0) ((float*)Cout)[(size_t)rowg * N + col] = v;
        else          ((u16*)Cout)[(size_t)rowg * N + col] = f2bf(v);
      }
    }
  }
}

// ---------------------------------------------------------------------------
// Weight transpose+convert: f32 [Ks][Ns] -> bf16 [Ns][Ks] at dstOff
// ---------------------------------------------------------------------------
struct WPtrs { const float* p[10]; };

__global__ __launch_bounds__(256) void wcvt(WPtrs wp, u16* __restrict__ dst) {
  constexpr int NE = 20;
  constexpr int srcIdx[NE] = {0,1,0,1,3,3,4,4,5,5,6,6,7,7,2,2,8,8,9,9};
  constexpr int srcOff[NE] = {0,0,262144,262144,0,262144,0,262144,0,262144,
                              0,262144,0,262144,0,262144,0,1048576,0,1048576};
  constexpr int dstOff[NE] = {0,262144,524288,786432,1048576,1310720,
                              1572864,1835008,2097152,2359296,2621440,2883584,
                              3145728,3407872,3670016,3932160,
                              4194304,5242880,6291456,7340032};
  constexpr int KsA[NE] = {512,512,512,512,512,512,512,512,512,512,
                           512,512,512,512,512,512,512,512,2048,2048};
  constexpr int NsA[NE] = {512,512,512,512,512,512,512,512,512,512,
                           512,512,512,512,512,512,2048,2048,512,512};
  constexpr int tileStart[NE] = {0,64,128,192,256,320,384,448,512,576,
                                 640,704,768,832,896,960,1024,1280,1536,1792};
  __shared__ float ts[64 * 65];
  const int tid = threadIdx.x;
  const int bid = blockIdx.x;
  int e = 0;
#pragma unroll
  for (int i = 1; i < NE; ++i) if (bid >= tileStart[i]) e = i;
  const int t = bid - tileStart[e];
  const int Ks_ = KsA[e], Ns_ = NsA[e];
  const int tn = t % (Ns_ >> 6), tk = t / (Ns_ >> 6);
  const float* src = wp.p[srcIdx[e]] + srcOff[e];

  {
    int r = tid >> 2, cb = (tid & 3) * 16;
    const float* sp = src + (size_t)(tk * 64 + r) * Ns_ + tn * 64 + cb;
#pragma unroll
    for (int j = 0; j < 4; ++j) {
      float4 v = ((const float4*)sp)[j];
      float* d = &ts[r * 65 + cb + j * 4];
      d[0] = v.x; d[1] = v.y; d[2] = v.z; d[3] = v.w;
    }
  }
  __syncthreads();
  {
    int n = tid >> 2, kb = (tid & 3) * 16;
    u16* dp = dst + dstOff[e] + (size_t)(tn * 64 + n) * Ks_ + tk * 64 + kb;
    s16x8 o0, o1;
#pragma unroll
    for (int j = 0; j < 8; ++j) o0[j] = (short)f2bf(ts[(kb + j) * 65 + n]);
#pragma unroll
    for (int j = 0; j < 8; ++j) o1[j] = (short)f2bf(ts[(kb + 8 + j) * 65 + n]);
    *(s16x8*)dp = o0;
    *(s16x8*)(dp + 8) = o1;
  }
}

// ---------------------------------------------------------------------------
// activations f32->bf16 (blocks 0..1023); block 1024: relv -> relv^T bf16
// ---------------------------------------------------------------------------
__global__ __launch_bounds__(256) void acvt(
    const float* __restrict__ q, const float* __restrict__ kv,
    const float* __restrict__ relv,
    u16* __restrict__ obf, u16* __restrict__ kvbf, u16* __restrict__ relvt) {
  int bid = blockIdx.x, tid = threadIdx.x;
  if (bid == 1024) {
    int d = tid >> 2, rb = (tid & 3) * 16;
    s16x8 o0, o1;
#pragma unroll
    for (int j = 0; j < 8; ++j) o0[j] = (short)f2bf(relv[(rb + j) * 64 + d]);
#pragma unroll
    for (int j = 0; j < 8; ++j) o1[j] = (short)f2bf(relv[(rb + 8 + j) * 64 + d]);
    *(s16x8*)(relvt + d * 64 + rb) = o0;
    *(s16x8*)(relvt + d * 64 + rb + 8) = o1;
    return;
  }
  int i = bid * 256 + tid;
  const float* src; u16* dst; size_t off;
  if (i < 131072) { src = q; dst = obf; off = (size_t)i * 8; }
  else { src = kv; dst = kvbf; off = (size_t)(i - 131072) * 8; }
  float4 a = *(const float4*)(src + off);
  float4 b = *(const float4*)(src + off + 4);
  s16x8 o;
  o[0] = (short)f2bf(a.x); o[1] = (short)f2bf(a.y);
  o[2] = (short)f2bf(a.z); o[3] = (short)f2bf(a.w);
  o[4] = (short)f2bf(b.x); o[5] = (short)f2bf(b.y);
  o[6] = (short)f2bf(b.z); o[7] = (short)f2bf(b.w);
  *(s16x8*)(dst + off) = o;
}

// ---------------------------------------------------------------------------
// Qr[(row*8+h), r] = sum_d Q[row, h*64+d] * relk[r, d]  (Q = bQK, stride 1024)
// ---------------------------------------------------------------------------
__global__ __launch_bounds__(256) void qr_kernel(
    const u16* __restrict__ Q, const float* __restrict__ relk,
    float* __restrict__ Qr) {
  __shared__ float rk[64 * 65];
  __shared__ float qs[4][64];
  const int tid = threadIdx.x;
  {
    int r = tid >> 2, cb = (tid & 3) * 16;
    const float* sp = relk + r * 64 + cb;
#pragma unroll
    for (int j = 0; j < 4; ++j) {
      float4 v = ((const float4*)sp)[j];
      float* d = &rk[r * 65 + cb + j * 4];
      d[0] = v.x; d[1] = v.y; d[2] = v.z; d[3] = v.w;
    }
  }
  const int sub = tid >> 6, r = tid & 63;
  const int unit = blockIdx.x * 4 + sub;  // unit = row*8 + h
  qs[sub][r] = bf2f(Q[(size_t)(unit >> 3) * 1024 + (unit & 7) * 64 + r]);
  __syncthreads();
  float acc = 0.f;
#pragma unroll
  for (int d = 0; d < 64; ++d) acc += qs[sub][d] * rk[r * 65 + d];
  Qr[(size_t)unit * 64 + r] = acc;
}

// ---------------------------------------------------------------------------
// Relation-aware masked self-attention. ONE WAVE per block, 16 q-rows.
// No K/V/rel LDS staging (L2-resident, direct fragment loads), no barriers.
// 2-deep manual prefetch of K+rel. Grid: (32 qtile16, 8 head, 4 batch).
// ---------------------------------------------------------------------------
#define RELID(RV, r) ((r) == 0 ? (RV).x : (r) == 1 ? (RV).y : (r) == 2 ? (RV).z : (RV).w)

#define LOADKREL(KF, RF, C8) do {                                              \
    _Pragma("unroll") for (int mt = 0; mt < 4; ++mt) {                         \
      KF[mt * 2 + 0] = *(const s16x8*)(kp + (size_t)(C8) * 65536 + mt * 16384);\
      KF[mt * 2 + 1] = *(const s16x8*)(kp + (size_t)(C8) * 65536 + mt * 16384 + 32); \
      RF[mt] = *(const int4*)(rp + (C8) * 64 + mt * 16);                       \
    } } while (0)

#define COMPUTE_SELF(KF, RF, C8) do {                                          \
    s16x8 vf[8];                                                               \
    _Pragma("unroll") for (int df = 0; df < 4; ++df) {                         \
      vf[df * 2 + 0] = *(const s16x8*)(vp + (size_t)(C8) * 64 + df * 32768);   \
      vf[df * 2 + 1] = *(const s16x8*)(vp + (size_t)(C8) * 64 + df * 32768 + 32); } \
    f32x4 sf[4];                                                               \
    _Pragma("unroll") for (int mt = 0; mt < 4; ++mt) {                         \
      sf[mt] = (f32x4){0.f, 0.f, 0.f, 0.f};                                    \
      sf[mt] = mfma_bf16(KF[mt * 2 + 0], aq0, sf[mt]);                         \
      sf[mt] = mfma_bf16(KF[mt * 2 + 1], aq1, sf[mt]); }                       \
    float p[4][4];                                                             \
    float pmax = NEGV;                                                         \
    _Pragma("unroll") for (int mt = 0; mt < 4; ++mt) {                         \
      _Pragma("unroll") for (int r = 0; r < 4; ++r) {                          \
        int rel = RELID(RF[mt], r);                                            \
        bool valid = (rel != 0) && ((C8) * 64 + mt * 16 + 4 * g + r <= lrow);  \
        p[mt][r] = valid ? (sf[mt][r] + qrs[li * 66 + rel]) * 0.125f : NEGV;   \
        pmax = fmaxf(pmax, p[mt][r]); } }                                      \
    pmax = fmaxf(pmax, __shfl_xor(pmax, 16));                                  \
    pmax = fmaxf(pmax, __shfl_xor(pmax, 32));                                  \
    if (__any(pmax > mrow + THRV)) {                                           \
      float mnew = (pmax > mrow + THRV) ? pmax : mrow;                         \
      float f = __expf(mrow - mnew);                                           \
      rsum *= f;                                                               \
      _Pragma("unroll") for (int j = 0; j < 8; ++j) {                          \
        float2* p2 = (float2*)&buck[li * 66 + g * 16 + 2 * j];                 \
        float2 v = *p2; v.x *= f; v.y *= f; *p2 = v; }                         \
      _Pragma("unroll") for (int r = 0; r < 4; ++r) {                          \
        float fr = __shfl(f, 4 * g + r);                                       \
        _Pragma("unroll") for (int df = 0; df < 4; ++df) oacc[df][r] *= fr; }  \
      mrow = mnew; }                                                           \
    unsigned pk[4][2];                                                         \
    _Pragma("unroll") for (int mt = 0; mt < 4; ++mt) {                         \
      _Pragma("unroll") for (int r = 0; r < 4; ++r) {                          \
        float pv = __expf(p[mt][r] - mrow);                                    \
        p[mt][r] = pv;                                                         \
        rsum += pv;                                                            \
        if (pv > 0.f) atomicAdd(&buck[li * 66 + RELID(RF[mt], r)], pv); }      \
      pk[mt][0] = cvtpk(p[mt][0], p[mt][1]);                                   \
      pk[mt][1] = cvtpk(p[mt][2], p[mt][3]); }                                 \
    _Pragma("unroll") for (int kk = 0; kk < 2; ++kk) {                         \
      union { s16x8 v; unsigned u[4]; } pa;                                    \
      _Pragma("unroll") for (int q = 0; q < 4; ++q) {                          \
        int src = ((2 * (g & 1) + (q >> 1)) << 4) + li;                        \
        unsigned uA = __shfl(pk[2 * kk][q & 1], src);                          \
        unsigned uB = __shfl(pk[2 * kk + 1][q & 1], src);                      \
        pa.u[q] = (g < 2) ? uA : uB; }                                         \
      _Pragma("unroll") for (int df = 0; df < 4; ++df)                         \
        oacc[df] = mfma_bf16(pa.v, vf[df * 2 + kk], oacc[df]); }               \
  } while (0)

__global__ __launch_bounds__(64) void attn_self(
    const u16* __restrict__ Qb, const u16* __restrict__ Kb,  // stride 1024
    const u16* __restrict__ VT,                              // [512][2048]
    const float* __restrict__ Qr, const int* __restrict__ rel_ids,
    const u16* __restrict__ relvt, u16* __restrict__ att) {
  __shared__ float qrs[16 * 66];
  __shared__ float buck[16 * 66];

  const int lane = threadIdx.x;
  const int g = lane >> 4, li = lane & 15;
  const int qt = blockIdx.x, h = blockIdx.y, b = blockIdx.z;
  const int lrow = qt * 16 + li;            // q-row within batch (this lane)
  const int growq = b * 512 + qt * 16;
  const int c_hi = qt >> 2;

  const u16* qp = Qb + (size_t)(growq + li) * 1024 + h * 64;
  s16x8 aq0 = *(const s16x8*)(qp + g * 8);
  s16x8 aq1 = *(const s16x8*)(qp + 32 + g * 8);
  const u16* kp = Kb + (size_t)(b * 512 + li) * 1024 + h * 64 + g * 8;
  const u16* vp = VT + (size_t)(h * 64 + li) * 2048 + b * 512 + g * 8;
  const int* rp = rel_ids + (size_t)(growq + li) * 512 + 4 * g;

#pragma unroll
  for (int j = 0; j < 4; ++j) {  // stage Qr (16x64) + zero buckets
    int fi = j * 64 + lane;
    int row = fi >> 4, c4 = (fi & 15) * 4;
    float4 v = *(const float4*)(Qr + ((size_t)(growq + row) * 8 + h) * 64 + c4);
    *(float4*)&qrs[row * 66 + c4] = v;
    *(float4*)&buck[row * 66 + c4] = make_float4(0.f, 0.f, 0.f, 0.f);
  }

  float mrow = NEGV, rsum = 0.f;
  f32x4 oacc[4];
#pragma unroll
  for (int d = 0; d < 4; ++d) oacc[d] = (f32x4){0.f, 0.f, 0.f, 0.f};

  s16x8 kA[8], kB[8];
  int4 rA[4], rB[4];
  LOADKREL(kA, rA, 0);
  int c8 = 0;
  for (;;) {
    if (c8 + 1 <= c_hi) LOADKREL(kB, rB, c8 + 1);
    COMPUTE_SELF(kA, rA, c8);
    if (++c8 > c_hi) break;
    if (c8 + 1 <= c_hi) LOADKREL(kA, rA, c8 + 1);
    COMPUTE_SELF(kB, rB, c8);
    if (++c8 > c_hi) break;
  }

  // fully-masked-row continuation (rare): uniform weight 1 over remaining cols
  if (__any(mrow == NEGV)) {
    float pm = (mrow == NEGV) ? 1.f : 0.f;
    union { s16x8 v; unsigned u[4]; } pa;
    unsigned pku = cvtpk(pm, pm);
#pragma unroll
    for (int q = 0; q < 4; ++q) pa.u[q] = pku;
    for (int c = c_hi + 1; c < 8; ++c) {
      if (pm > 0.f) {
        rsum += 16.f;
#pragma unroll
        for (int mt = 0; mt < 4; ++mt) {
          int4 rv = *(const int4*)(rp + c * 64 + mt * 16);
#pragma unroll
          for (int r = 0; r < 4; ++r) atomicAdd(&buck[li * 66 + RELID(rv, r)], 1.f);
        }
      }
#pragma unroll
      for (int kk = 0; kk < 2; ++kk)
#pragma unroll
        for (int df = 0; df < 4; ++df) {
          s16x8 bv = *(const s16x8*)(vp + (size_t)c * 64 + df * 32768 + kk * 32);
          oacc[df] = mfma_bf16(pa.v, bv, oacc[df]);
        }
    }
  }

  rsum += __shfl_xor(rsum, 16);
  rsum += __shfl_xor(rsum, 32);

  // rel-V: oacc += buck @ relv  (A = buck rows, B = relv^T)
#pragma unroll
  for (int kk = 0; kk < 2; ++kk) {
    float bb[8];
#pragma unroll
    for (int j = 0; j < 4; ++j) {
      float2 v = *(const float2*)&buck[li * 66 + kk * 32 + g * 8 + 2 * j];
      bb[2 * j] = v.x; bb[2 * j + 1] = v.y;
    }
    union { s16x8 v; unsigned u[4]; } pb;
#pragma unroll
    for (int q = 0; q < 4; ++q) pb.u[q] = cvtpk(bb[2 * q], bb[2 * q + 1]);
#pragma unroll
    for (int df = 0; df < 4; ++df) {
      s16x8 rb = *(const s16x8*)(relvt + (df * 16 + li) * 64 + kk * 32 + g * 8);
      oacc[df] = mfma_bf16(pb.v, rb, oacc[df]);
    }
  }

  float inv[4];
#pragma unroll
  for (int r = 0; r < 4; ++r) inv[r] = 1.f / __shfl(rsum, 4 * g + r);
#pragma unroll
  for (int df = 0; df < 4; ++df)
#pragma unroll
    for (int r = 0; r < 4; ++r)
      att[(size_t)(growq + 4 * g + r) * 512 + h * 64 + df * 16 + li] =
          f2bf(oacc[df][r] * inv[r]);
}

// ---------------------------------------------------------------------------
// Cross-attention (no mask): ONE WAVE per block, 16 q-rows, no LDS, no
// barriers, direct global fragment loads, 2-deep K prefetch.
// Grid: (32 qtile16, 8 head, 4 batch)
// ---------------------------------------------------------------------------
#define LOADK_X(KF, C8) do {                                                   \
    _Pragma("unroll") for (int mt = 0; mt < 4; ++mt) {                         \
      KF[mt * 2 + 0] = *(const s16x8*)(kp + (size_t)(C8) * 65536 + mt * 16384);\
      KF[mt * 2 + 1] = *(const s16x8*)(kp + (size_t)(C8) * 65536 + mt * 16384 + 32); \
    } } while (0)

#define COMPUTE_X(KF, C8) do {                                                 \
    s16x8 vf[8];                                                               \
    _Pragma("unroll") for (int df = 0; df < 4; ++df) {                         \
      vf[df * 2 + 0] = *(const s16x8*)(vp + (size_t)(C8) * 64 + df * 32768);   \
      vf[df * 2 + 1] = *(const s16x8*)(vp + (size_t)(C8) * 64 + df * 32768 + 32); } \
    f32x4 sf[4];                                                               \
    _Pragma("unroll") for (int mt = 0; mt < 4; ++mt) {                         \
      sf[mt] = (f32x4){0.f, 0.f, 0.f, 0.f};                                    \
      sf[mt] = mfma_bf16(KF[mt * 2 + 0], aq0, sf[mt]);                         \
      sf[mt] = mfma_bf16(KF[mt * 2 + 1], aq1, sf[mt]); }                       \
    float p[4][4];                                                             \
    float pmax = NEGV;                                                         \
    _Pragma("unroll") for (int mt = 0; mt < 4; ++mt)                           \
      _Pragma("unroll") for (int r = 0; r < 4; ++r) {                          \
        p[mt][r] = sf[mt][r] * 0.125f;                                         \
        pmax = fmaxf(pmax, p[mt][r]); }                                        \
    pmax = fmaxf(pmax, __shfl_xor(pmax, 16));                                  \
    pmax = fmaxf(pmax, __shfl_xor(pmax, 32));                                  \
    if (__any(pmax > mrow + THRV)) {                                           \
      float mnew = (pmax > mrow + THRV) ? pmax : mrow;                         \
      float f = __expf(mrow - mnew);                                           \
      rsum *= f;                                                               \
      _Pragma("unroll") for (int r = 0; r < 4; ++r) {                          \
        float fr = __shfl(f, 4 * g + r);                                       \
        _Pragma("unroll") for (int df = 0; df < 4; ++df) oacc[df][r] *= fr; }  \
      mrow = mnew; }                                                           \
    unsigned pk[4][2];                                                         \
    _Pragma("unroll") for (int mt = 0; mt < 4; ++mt) {                         \
      _Pragma("unroll") for (int r = 0; r < 4; ++r) {                          \
        float pv = __expf(p[mt][r] - mrow);                                    \
        p[mt][r] = pv;                                                         \
        rsum += pv; }                                                          \
      pk[mt][0] = cvtpk(p[mt][0], p[mt][1]);                                   \
      pk[mt][1] = cvtpk(p[mt][2], p[mt][3]); }                                 \
    _Pragma("unroll") for (int kk = 0; kk < 2; ++kk) {                         \
      union { s16x8 v; unsigned u[4]; } pa;                                    \
      _Pragma("unroll") for (int q = 0; q < 4; ++q) {                          \
        int src = ((2 * (g & 1) + (q >> 1)) << 4) + li;                        \
        unsigned uA = __shfl(pk[2 * kk][q & 1], src);                          \
        unsigned uB = __shfl(pk[2 * kk + 1][q & 1], src);                      \
        pa.u[q] = (g < 2) ? uA : uB; }                                         \
      _Pragma("unroll") for (int df = 0; df < 4; ++df)                         \
        oacc[df] = mfma_bf16(pa.v, vf[df * 2 + kk], oacc[df]); }               \
  } while (0)

__global__ __launch_bounds__(64) void attn_cross(
    const u16* __restrict__ Qb,   // stride 512
    const u16* __restrict__ Kb,   // stride 1024
    const u16* __restrict__ VT,   // stride 2048
    u16* __restrict__ att) {
  const int lane = threadIdx.x;
  const int g = lane >> 4, li = lane & 15;
  const int qt = blockIdx.x, h = blockIdx.y, b = blockIdx.z;
  const int growq = b * 512 + qt * 16;

  const u16* qp = Qb + (size_t)(growq + li) * 512 + h * 64;
  s16x8 aq0 = *(const s16x8*)(qp + g * 8);
  s16x8 aq1 = *(const s16x8*)(qp + 32 + g * 8);
  const u16* kp = Kb + (size_t)(b * 512 + li) * 1024 + h * 64 + g * 8;
  const u16* vp = VT + (size_t)(h * 64 + li) * 2048 + b * 512 + g * 8;

  float mrow = NEGV, rsum = 0.f;
  f32x4 oacc[4];
#pragma unroll
  for (int d = 0; d < 4; ++d) oacc[d] = (f32x4){0.f, 0.f, 0.f, 0.f};

  s16x8 kA[8], kB[8];
  LOADK_X(kA, 0);
  for (int c8 = 0; c8 < 8; c8 += 2) {
    LOADK_X(kB, c8 + 1);
    COMPUTE_X(kA, c8);
    if (c8 + 2 < 8) LOADK_X(kA, c8 + 2);
    COMPUTE_X(kB, c8 + 1);
  }

  rsum += __shfl_xor(rsum, 16);
  rsum += __shfl_xor(rsum, 32);
  float inv[4];
#pragma unroll
  for (int r = 0; r < 4; ++r) inv[r] = 1.f / __shfl(rsum, 4 * g + r);
#pragma unroll
  for (int df = 0; df < 4; ++df)
#pragma unroll
    for (int r = 0; r < 4; ++r)
      att[(size_t)(growq + 4 * g + r) * 512 + h * 64 + df * 16 + li] =
          f2bf(oacc[df][r] * inv[r]);
}

// ---------------------------------------------------------------------------
// out = LayerNorm(x + dlt) * g + b ; also writes bf16 copy
// ---------------------------------------------------------------------------
__global__ __launch_bounds__(256) void ln_res(
    const float* __restrict__ x, const float* __restrict__ dlt,
    const float* __restrict__ g, const float* __restrict__ bta,
    float* __restrict__ out, u16* __restrict__ obf) {
  __shared__ float red_s[256];
  const int row = blockIdx.x, tid = threadIdx.x;
  const size_t base = (size_t)row * Hc;
  float v0 = x[base + tid] + dlt[base + tid];
  float v1 = x[base + tid + 256] + dlt[base + tid + 256];

  red_s[tid] = v0 + v1;
  __syncthreads();
  for (int s = 128; s > 0; s >>= 1) {
    if (tid < s) red_s[tid] += red_s[tid + s];
    __syncthreads();
  }
  const float mean = red_s[0] * (1.f / Hc);
  __syncthreads();
  const float d0 = v0 - mean, d1 = v1 - mean;
  red_s[tid] = d0 * d0 + d1 * d1;
  __syncthreads();
  for (int s = 128; s > 0; s >>= 1) {
    if (tid < s) red_s[tid] += red_s[tid + s];
    __syncthreads();
  }
  const float rstd = rsqrtf(red_s[0] * (1.f / Hc) + EPSV);
  float o0 = d0 * rstd * g[tid] + bta[tid];
  float o1 = d1 * rstd * g[tid + 256] + bta[tid + 256];
  out[base + tid] = o0;
  out[base + tid + 256] = o1;
  obf[base + tid] = f2bf(o0);
  obf[base + tid + 256] = f2bf(o1);
}

// ---------------------------------------------------------------------------
extern "C" void kernel_launch(void* const* d_in, const int* in_sizes, int n_in,
                              void* d_out, int out_size, void* d_ws, size_t ws_size,
                              hipStream_t stream) {
  const float* q    = (const float*)d_in[0];
  const float* kv   = (const float*)d_in[1];
  const float* relk = (const float*)d_in[2];
  const float* relv = (const float*)d_in[3];
  const float* Wq_s = (const float*)d_in[4];
  const float* bq_s = (const float*)d_in[5];
  const float* Wk_s = (const float*)d_in[6];
  const float* Wv_s = (const float*)d_in[7];
  const float* Wo_s = (const float*)d_in[8];
  const float* bo_s = (const float*)d_in[9];
  const float* ln1g = (const float*)d_in[10];
  const float* ln1b = (const float*)d_in[11];
  const float* Wq_c = (const float*)d_in[12];
  const float* bq_c = (const float*)d_in[13];
  const float* Wk_c = (const float*)d_in[14];
  const float* Wv_c = (const float*)d_in[15];
  const float* Wo_c = (const float*)d_in[16];
  const float* bo_c = (const float*)d_in[17];
  const float* ln2g = (const float*)d_in[18];
  const float* ln2b = (const float*)d_in[19];
  const float* W1   = (const float*)d_in[20];
  const float* b1   = (const float*)d_in[21];
  const float* W2   = (const float*)d_in[22];
  const float* b2   = (const float*)d_in[23];
  const float* ln3g = (const float*)d_in[24];
  const float* ln3b = (const float*)d_in[25];
  const int*   rel  = (const int*)d_in[26];

  char* wsb = (char*)d_ws;
  const size_t NT = (size_t)Bc * Tc;  // 2048 token rows
  float* o     = (float*)wsb;  wsb += NT * Hc * 4;       // 4MB
  float* bDlt  = (float*)wsb;  wsb += NT * Hc * 4;       // 4MB
  float* Qr    = (float*)wsb;  wsb += NT * 8 * 64 * 4;   // 4MB
  u16* obf     = (u16*)wsb;    wsb += NT * Hc * 2;       // 2MB
  u16* kvbf    = (u16*)wsb;    wsb += NT * Hc * 2;       // 2MB
  u16* bQK     = (u16*)wsb;    wsb += NT * 1024 * 2;     // 4MB
  u16* bVt     = (u16*)wsb;    wsb += (size_t)512 * 2048 * 2;   // 2MB
  u16* bQc     = (u16*)wsb;    wsb += NT * Hc * 2;       // 2MB
  u16* bKc     = (u16*)wsb;    wsb += NT * 1024 * 2;     // 4MB
  u16* bVtc    = (u16*)wsb;    wsb += (size_t)1024 * 2048 * 2;  // 4MB
  u16* bAtt    = (u16*)wsb;    wsb += NT * Hc * 2;       // 2MB
  u16* bH      = (u16*)wsb;    wsb += NT * FFc * 2;      // 8MB
  u16* relvt   = (u16*)wsb;    wsb += 64 * 64 * 2;       // 8KB
  u16* wbuf    = (u16*)wsb;    wsb += (size_t)8388608 * 2;  // 16MB

  WPtrs wp;
  wp.p[0] = Wq_s; wp.p[1] = Wk_s; wp.p[2] = Wv_s; wp.p[3] = Wo_s;
  wp.p[4] = Wq_c; wp.p[5] = Wk_c; wp.p[6] = Wv_c; wp.p[7] = Wo_c;
  wp.p[8] = W1;   wp.p[9] = W2;

  dim3 blk(256);
  wcvt<<<dim3(2048), blk, 0, stream>>>(wp, wbuf);
  acvt<<<dim3(1025), blk, 0, stream>>>(q, kv, relv, obf, kvbf, relvt);
  hipMemcpyAsync(o, q, NT * Hc * 4, hipMemcpyDeviceToDevice, stream);

  // cross K (both layers) and cross V^T (both layers)
  gemm_mfma<64, 128, false, 1><<<dim3(8, 32), blk, 0, stream>>>(
      kvbf, wbuf + 2097152, nullptr, 0, bKc, 1024, 512);
  gemm_mfma<64, 128, false, 1><<<dim3(16, 16), blk, 0, stream>>>(
      wbuf + 2621440, kvbf, nullptr, 0, bVtc, 2048, 512);

  const dim3 gLN(NT);
  const dim3 gATT(32, 8, 4);
  for (int i = 0; i < NLc; ++i) {
    // --- relation-aware masked self-attention ---
    gemm_mfma<64, 128, false, 1><<<dim3(8, 32), blk, 0, stream>>>(
        obf, wbuf + (size_t)i * 524288, bq_s + i * Hc, Hc, bQK, 1024, 512);
    gemm_mfma<64, 64, false, 1><<<dim3(32, 8), blk, 0, stream>>>(
        wbuf + 3670016 + (size_t)i * 262144, obf, nullptr, 0, bVt, 2048, 512);
    qr_kernel<<<dim3(4096), blk, 0, stream>>>(bQK, relk, Qr);
    attn_self<<<gATT, dim3(64), 0, stream>>>(
        bQK, bQK + 512, bVt, Qr, rel, relvt, bAtt);
    gemm_mfma<64, 64, false, 0><<<dim3(8, 32), blk, 0, stream>>>(
        bAtt, wbuf + 1048576 + (size_t)i * 262144, bo_s + i * Hc, Hc, bDlt, Hc, 512);
    ln_res<<<gLN, blk, 0, stream>>>(o, bDlt, ln1g + i * Hc, ln1b + i * Hc, o, obf);

    // --- cross-attention ---
    gemm_mfma<64, 64, false, 1><<<dim3(8, 32), blk, 0, stream>>>(
        obf, wbuf + 1572864 + (size_t)i * 262144, bq_c + i * Hc, Hc, bQc, Hc, 512);
    attn_cross<<<gATT, dim3(64), 0, stream>>>(
        bQc, bKc + i * 512, bVtc + (size_t)i * 512 * 2048, bAtt);
    gemm_mfma<64, 64, false, 0><<<dim3(8, 32), blk, 0, stream>>>(
        bAtt, wbuf + 3145728 + (size_t)i * 262144, bo_c + i * Hc, Hc, bDlt, Hc, 512);
    ln_res<<<gLN, blk, 0, stream>>>(o, bDlt, ln2g + i * Hc, ln2b + i * Hc, o, obf);

    // --- feedforward ---
    gemm_mfma<128, 128, true, 1><<<dim3(16, 16), blk, 0, stream>>>(
        obf, wbuf + 4194304 + (size_t)i * 1048576, b1 + i * FFc, FFc, bH, FFc, 512);
    gemm_mfma<64, 64, false, 0><<<dim3(8, 32), blk, 0, stream>>>(
        bH, wbuf + 6291456 + (size_t)i * 1048576, b2 + i * Hc, Hc, bDlt, Hc, 2048);
    float* lnout = (i == NLc - 1) ? (float*)d_out : o;
    ln_res<<<gLN, blk, 0, stream>>>(o, bDlt, ln3g + i * Hc, ln3b + i * Hc, lnout, obf);
  }
}